// Round 3
// baseline (5393.292 us; speedup 1.0000x reference)
//
#include <hip/hip_runtime.h>
#include <math.h>

#define BB 2
#define DD 256
#define HH 8
#define HDIM 32
#define FFD 1024
#define LL 6
#define NQQ 540
#define QPO_ 27
#define PS0 20
#define PS1 20
#define PS2 32
#define PP (PS0*PS1*PS2)   // 12800
#define MR (BB*NQQ)        // 1080

static __device__ __forceinline__ float wred_sum(float x) {
#pragma unroll
  for (int off = 32; off; off >>= 1) x += __shfl_xor(x, off, 64);
  return x;
}
static __device__ __forceinline__ float wred_max(float x) {
#pragma unroll
  for (int off = 32; off; off >>= 1) x = fmaxf(x, __shfl_xor(x, off, 64));
  return x;
}

// ---------------------------------------------------------------------------
// init: tgt[b,q,d] = qe[q, 256+d]; qpos[b,q,d] = qe[q, d]
__global__ __launch_bounds__(256) void init_kernel(
    const float* __restrict__ qe, float* __restrict__ tgt, float* __restrict__ qpos)
{
  int idx = blockIdx.x * 256 + threadIdx.x;   // < B*NQ*D == 276480
  int d = idx % DD;
  int q = (idx / DD) % NQQ;
  qpos[idx] = qe[q * 512 + d];
  tgt[idx]  = qe[q * 512 + 256 + d];
}

// ---------------------------------------------------------------------------
// Generic row GEMM: C[r,n] = sum_k (A1[r,k] (+A2[r,k])) * W[n,k] (+bias) (+res) (relu?)
// BM=BN=64, BK=16, 256 threads, 4x4 per thread.
__global__ __launch_bounds__(256) void gemm_rows(
    const float* __restrict__ A1, const float* __restrict__ A2,
    const float* __restrict__ W, const float* __restrict__ bias,
    const float* __restrict__ res, float* __restrict__ C,
    int M, int N, int K, int relu)
{
  __shared__ float a_s[16][65];
  __shared__ float w_s[64][17];
  int bm = blockIdx.x * 64;
  int bn = blockIdx.y * 64;
  int t = threadIdx.x;
  int tp = t & 15, to = t >> 4;
  float acc[4][4] = {};
  for (int k0 = 0; k0 < K; k0 += 16) {
    { // A tile: 64 rows x 16 k, one float4 per thread
      int rl = t >> 2;
      int kq = (t & 3) * 4;
      int r = bm + rl;
      float4 av = make_float4(0.f, 0.f, 0.f, 0.f);
      if (r < M) {
        av = *(const float4*)&A1[(size_t)r * K + k0 + kq];
        if (A2) {
          float4 bv = *(const float4*)&A2[(size_t)r * K + k0 + kq];
          av.x += bv.x; av.y += bv.y; av.z += bv.z; av.w += bv.w;
        }
      }
      a_s[kq + 0][rl] = av.x; a_s[kq + 1][rl] = av.y;
      a_s[kq + 2][rl] = av.z; a_s[kq + 3][rl] = av.w;
    }
    { // W tile: 64 n x 16 k
      int ol = t >> 2;
      int kq = (t & 3) * 4;
      float4 wv = *(const float4*)&W[(size_t)(bn + ol) * K + k0 + kq];
      w_s[ol][kq + 0] = wv.x; w_s[ol][kq + 1] = wv.y;
      w_s[ol][kq + 2] = wv.z; w_s[ol][kq + 3] = wv.w;
    }
    __syncthreads();
#pragma unroll
    for (int d = 0; d < 16; ++d) {
      float a[4], w[4];
#pragma unroll
      for (int i = 0; i < 4; ++i) a[i] = a_s[d][tp * 4 + i];
#pragma unroll
      for (int j = 0; j < 4; ++j) w[j] = w_s[to * 4 + j][d];
#pragma unroll
      for (int i = 0; i < 4; ++i)
#pragma unroll
        for (int j = 0; j < 4; ++j)
          acc[i][j] = fmaf(a[i], w[j], acc[i][j]);
    }
    __syncthreads();
  }
#pragma unroll
  for (int i = 0; i < 4; ++i) {
    int r = bm + tp * 4 + i;
    if (r >= M) continue;
#pragma unroll
    for (int j = 0; j < 4; ++j) {
      int n = bn + to * 4 + j;
      float v = acc[i][j];
      if (bias) v += bias[n];
      if (relu) v = fmaxf(v, 0.f);
      if (res)  v += res[(size_t)r * N + n];
      C[(size_t)r * N + n] = v;
    }
  }
}

// ---------------------------------------------------------------------------
// K/V projection GEMM. A(r=p, k=d) = src[b,d,p] (+pos[b,d,p]); W (256,256) row-major (o,d).
// Output layout: out[b][h][p][hd], n = h*32+hd.
__global__ __launch_bounds__(256) void gemm_kv(
    const float* __restrict__ src, const float* __restrict__ pos,
    const float* __restrict__ W, float* __restrict__ out)
{
  __shared__ float a_s[16][65];
  __shared__ float w_s[64][17];
  int b = blockIdx.z;
  int p0 = blockIdx.x * 64;
  int n0 = blockIdx.y * 64;
  int t = threadIdx.x;
  int tp = t & 15, to = t >> 4;
  const float* sb = src + (size_t)b * DD * PP;
  const float* pb = pos ? pos + (size_t)b * DD * PP : nullptr;
  float acc[4][4] = {};
  for (int k0 = 0; k0 < DD; k0 += 16) {
    { // A tile: a_s[dl][pl] = src[b][k0+dl][p0+pl] (+pos). contiguous in p -> coalesced
      int dl = t >> 4;
      int pq = (t & 15) * 4;
      float4 av = *(const float4*)&sb[(size_t)(k0 + dl) * PP + p0 + pq];
      if (pb) {
        float4 pv = *(const float4*)&pb[(size_t)(k0 + dl) * PP + p0 + pq];
        av.x += pv.x; av.y += pv.y; av.z += pv.z; av.w += pv.w;
      }
      a_s[dl][pq + 0] = av.x; a_s[dl][pq + 1] = av.y;
      a_s[dl][pq + 2] = av.z; a_s[dl][pq + 3] = av.w;
    }
    {
      int ol = t >> 2;
      int kq = (t & 3) * 4;
      float4 wv = *(const float4*)&W[(size_t)(n0 + ol) * DD + k0 + kq];
      w_s[ol][kq + 0] = wv.x; w_s[ol][kq + 1] = wv.y;
      w_s[ol][kq + 2] = wv.z; w_s[ol][kq + 3] = wv.w;
    }
    __syncthreads();
#pragma unroll
    for (int d = 0; d < 16; ++d) {
      float a[4], w[4];
#pragma unroll
      for (int i = 0; i < 4; ++i) a[i] = a_s[d][tp * 4 + i];
#pragma unroll
      for (int j = 0; j < 4; ++j) w[j] = w_s[to * 4 + j][d];
#pragma unroll
      for (int i = 0; i < 4; ++i)
#pragma unroll
        for (int j = 0; j < 4; ++j)
          acc[i][j] = fmaf(a[i], w[j], acc[i][j]);
    }
    __syncthreads();
  }
#pragma unroll
  for (int i = 0; i < 4; ++i) {
    int p = p0 + tp * 4 + i;
#pragma unroll
    for (int j = 0; j < 4; ++j) {
      int n = n0 + to * 4 + j;
      int h = n >> 5, hd = n & 31;
      out[((size_t)(b * HH + h) * PP + p) * HDIM + hd] = acc[i][j];
    }
  }
}

// ---------------------------------------------------------------------------
// Self-attention: one wave per (b,h,q), 540 keys, no mask.
// qkbuf: (MR,512) q cols 0..255, k cols 256..511. vbuf: (MR,256). out: (MR,256).
__global__ __launch_bounds__(256) void sa_attn(
    const float* __restrict__ qkbuf, const float* __restrict__ vbuf,
    float* __restrict__ out)
{
  __shared__ float plds[4][NQQ];
  int wv = threadIdx.x >> 6;
  int lane = threadIdx.x & 63;
  int wid = blockIdx.x * 4 + wv;
  int q = wid % NQQ;
  int h = (wid / NQQ) % HH;
  int b = wid / (NQQ * HH);
  const float scale = 0.17677669529663687f;  // 32^-0.5

  const float* qp = qkbuf + (size_t)(b * NQQ + q) * 512 + h * 32;
  float4 q4[8];
#pragma unroll
  for (int u = 0; u < 8; ++u) q4[u] = ((const float4*)qp)[u];

  const float* kb = qkbuf + (size_t)b * NQQ * 512 + 256 + h * 32;
  float lg[9];
  float mx = -INFINITY;
#pragma unroll
  for (int j = 0; j < 9; ++j) {
    int k = lane + j * 64;
    float s = -INFINITY;
    if (k < NQQ) {
      const float4* kp = (const float4*)(kb + (size_t)k * 512);
      float acc = 0.f;
#pragma unroll
      for (int u = 0; u < 8; ++u) {
        float4 kv4 = kp[u];
        acc = fmaf(q4[u].x, kv4.x, acc);
        acc = fmaf(q4[u].y, kv4.y, acc);
        acc = fmaf(q4[u].z, kv4.z, acc);
        acc = fmaf(q4[u].w, kv4.w, acc);
      }
      s = acc * scale;
    }
    lg[j] = s;
    mx = fmaxf(mx, s);
  }
  mx = wred_max(mx);
  float ssum = 0.f;
#pragma unroll
  for (int j = 0; j < 9; ++j) {
    int k = lane + j * 64;
    if (k < NQQ) {
      float p = __expf(lg[j] - mx);
      plds[wv][k] = p;
      ssum += p;
    }
  }
  ssum = wred_sum(ssum);

  int dow = lane & 31, half = lane >> 5;
  const float* vb = vbuf + (size_t)b * NQQ * 256 + h * 32 + dow;
  float oa0 = 0.f, oa1 = 0.f, oa2 = 0.f, oa3 = 0.f;
  int k = half;
  for (; k + 6 < NQQ; k += 8) {
    float p0 = plds[wv][k],     p1 = plds[wv][k + 2];
    float p2 = plds[wv][k + 4], p3 = plds[wv][k + 6];
    oa0 = fmaf(p0, vb[(size_t)k * 256],       oa0);
    oa1 = fmaf(p1, vb[(size_t)(k + 2) * 256], oa1);
    oa2 = fmaf(p2, vb[(size_t)(k + 4) * 256], oa2);
    oa3 = fmaf(p3, vb[(size_t)(k + 6) * 256], oa3);
  }
  for (; k < NQQ; k += 2)
    oa0 = fmaf(plds[wv][k], vb[(size_t)k * 256], oa0);
  float oa = (oa0 + oa1) + (oa2 + oa3);
  oa += __shfl_xor(oa, 32, 64);
  if (lane < 32)
    out[(size_t)(b * NQQ + q) * 256 + h * 32 + lane] = oa / ssum;
}

// ---------------------------------------------------------------------------
// Cross-attention with box mask. One BLOCK (4 waves) per (b,h,q).
// Fully lane-local online softmax: each lane owns its keys (private m,s,o[32];
// QK and PV both from the lane's own K/V rows; no cross-lane ops in hot loop).
// 256 lane-states merged once at the end via LDS.
// qbuf: (MR,256). Kbuf/Vbuf: [b][h][p][hd]. lohi: (MR,6).
__global__ __launch_bounds__(256) void ca_attn(
    const float* __restrict__ qbuf, const float* __restrict__ Kbuf,
    const float* __restrict__ Vbuf, const int* __restrict__ lohi,
    float* __restrict__ out)
{
  __shared__ float oo[256][33];   // padded: (l+d)%32 banks -> 2-way max (free)
  __shared__ float wm[4], wsum[4];
  __shared__ float pp[8][32];
  int wv = threadIdx.x >> 6;
  int lane = threadIdx.x & 63;
  int wid = blockIdx.x;
  int q = wid % NQQ;
  int h = (wid / NQQ) % HH;
  int b = wid / (NQQ * HH);
  const float scale = 0.17677669529663687f;

  const int* lh = lohi + (size_t)(b * NQQ + q) * 6;
  int lo0 = lh[0], lo1 = lh[1], lo2 = lh[2];
  int nx = lh[3] - lo0, ny = lh[4] - lo1, nz = lh[5] - lo2;
  int nyz = ny * nz;
  int nk = nx * nyz;
  float inv_nyz = 1.0f / (float)nyz;
  float inv_nz  = 1.0f / (float)nz;

  const float* qp = qbuf + (size_t)(b * NQQ + q) * 256 + h * 32;
  float4 q4[8];
#pragma unroll
  for (int u = 0; u < 8; ++u) q4[u] = ((const float4*)qp)[u];

  const float* Kb = Kbuf + (size_t)(b * HH + h) * PP * HDIM;
  const float* Vb = Vbuf + (size_t)(b * HH + h) * PP * HDIM;

  float m = -INFINITY, s = 0.f;
  float o[32];
#pragma unroll
  for (int d = 0; d < 32; ++d) o[d] = 0.f;

  for (int t0 = wv * 64; t0 < nk; t0 += 256) {
    int t = t0 + lane;
    if (t < nk) {
      // decompose t -> (x,y,z) with float-recip division + fixup
      int x = (int)((float)t * inv_nyz);
      int r = t - x * nyz;
      if (r < 0)        { x--; r += nyz; }
      else if (r >= nyz){ x++; r -= nyz; }
      int y = (int)((float)r * inv_nz);
      int z = r - y * nz;
      if (z < 0)        { y--; z += nz; }
      else if (z >= nz) { y++; z -= nz; }
      int pidx = (lo0 + x) * (PS1 * PS2) + (lo1 + y) * PS2 + (lo2 + z);

      const float4* kp = (const float4*)(Kb + (size_t)pidx * HDIM);
      const float4* vp = (const float4*)(Vb + (size_t)pidx * HDIM);
      float4 kv[8], vv[8];
#pragma unroll
      for (int u = 0; u < 8; ++u) kv[u] = kp[u];
#pragma unroll
      for (int u = 0; u < 8; ++u) vv[u] = vp[u];

      float acc = 0.f;
#pragma unroll
      for (int u = 0; u < 8; ++u) {
        acc = fmaf(q4[u].x, kv[u].x, acc);
        acc = fmaf(q4[u].y, kv[u].y, acc);
        acc = fmaf(q4[u].z, kv[u].z, acc);
        acc = fmaf(q4[u].w, kv[u].w, acc);
      }
      float lg = acc * scale;

      if (lg > m) {                       // lane-local new max (rare later)
        float c = __expf(m - lg);         // m=-inf first time -> c=0
        s *= c;
#pragma unroll
        for (int d = 0; d < 32; ++d) o[d] *= c;
        m = lg;
      }
      float p = __expf(lg - m);
      s += p;
#pragma unroll
      for (int u = 0; u < 8; ++u) {
        o[u * 4 + 0] = fmaf(p, vv[u].x, o[u * 4 + 0]);
        o[u * 4 + 1] = fmaf(p, vv[u].y, o[u * 4 + 1]);
        o[u * 4 + 2] = fmaf(p, vv[u].z, o[u * 4 + 2]);
        o[u * 4 + 3] = fmaf(p, vv[u].w, o[u * 4 + 3]);
      }
    }
  }

  // ---- merge 256 lane-states ----
  float wmax = wred_max(m);
  if (lane == 0) wm[wv] = wmax;
  __syncthreads();
  float M = fmaxf(fmaxf(wm[0], wm[1]), fmaxf(wm[2], wm[3]));
  float f = __expf(m - M);                // m=-inf (no keys) -> f=0
  float sf = wred_sum(s * f);
  if (lane == 0) wsum[wv] = sf;
  int l256 = threadIdx.x;
#pragma unroll
  for (int d = 0; d < 32; ++d) oo[l256][d] = o[d] * f;
  __syncthreads();
  {
    int d = threadIdx.x & 31, g = threadIdx.x >> 5;
    float part = 0.f;
#pragma unroll
    for (int i = 0; i < 32; ++i) part += oo[g * 32 + i][d];
    pp[g][d] = part;
  }
  __syncthreads();
  if (threadIdx.x < 32) {
    float den = (wsum[0] + wsum[1]) + (wsum[2] + wsum[3]);
    float num = 0.f;
#pragma unroll
    for (int gg = 0; gg < 8; ++gg) num += pp[gg][threadIdx.x];
    out[(size_t)(b * NQQ + q) * 256 + h * 32 + threadIdx.x] = num / den;
  }
}

// ---------------------------------------------------------------------------
// LayerNorm over D=256: one wave per row. x already contains residual sum.
__global__ __launch_bounds__(256) void ln_kernel(
    const float* __restrict__ x, const float* __restrict__ g,
    const float* __restrict__ bta, float* __restrict__ out)
{
  int wv = threadIdx.x >> 6;
  int lane = threadIdx.x & 63;
  int row = blockIdx.x * 4 + wv;
  const float* xr = x + (size_t)row * 256;
  float v[4];
#pragma unroll
  for (int j = 0; j < 4; ++j) v[j] = xr[lane + 64 * j];
  float s = v[0] + v[1] + v[2] + v[3];
  s = wred_sum(s);
  float mean = s * (1.f / 256.f);
  float vs = 0.f;
#pragma unroll
  for (int j = 0; j < 4; ++j) { float d = v[j] - mean; vs = fmaf(d, d, vs); }
  vs = wred_sum(vs);
  float inv = rsqrtf(vs * (1.f / 256.f) + 1e-5f);
  float* orow = out + (size_t)row * 256;
#pragma unroll
  for (int j = 0; j < 4; ++j) {
    int c = lane + 64 * j;
    orow[c] = (v[j] - mean) * inv * g[c] + bta[c];
  }
}

// ---------------------------------------------------------------------------
// Layer-0 mask boxes from attn_area.
__global__ __launch_bounds__(256) void mask0_kernel(
    const float* __restrict__ area, int* __restrict__ lohi,
    float px, float py, float pz)
{
  int row = blockIdx.x * 256 + threadIdx.x;
  if (row >= MR) return;
  int q = row % NQQ;
  int org = q / QPO_;
  const float* a = area + org * 6;
  int* o = lohi + (size_t)row * 6;
  o[0] = (int)fminf(fmaxf(floorf(a[0] * 20.f - px), 0.f), 20.f);
  o[1] = (int)fminf(fmaxf(floorf(a[1] * 20.f - py), 0.f), 20.f);
  o[2] = (int)fminf(fmaxf(floorf(a[2] * 32.f - pz), 0.f), 32.f);
  o[3] = (int)fminf(fmaxf(floorf(a[3] * 20.f + px), 0.f), 20.f);
  o[4] = (int)fminf(fmaxf(floorf(a[4] * 20.f + py), 0.f), 20.f);
  o[5] = (int)fminf(fmaxf(floorf(a[5] * 32.f + pz), 0.f), 32.f);
}

// ---------------------------------------------------------------------------
// Layers >=1: prop = h2 @ w3.T + b3 -> tanh*0.1 + anchors -> clip -> box ints.
// One wave per (b,q) row.
__global__ __launch_bounds__(256) void mask_reg_kernel(
    const float* __restrict__ h2, const float* __restrict__ w3,
    const float* __restrict__ b3, const float* __restrict__ anchors,
    int* __restrict__ lohi, float px, float py, float pz)
{
  int wv = threadIdx.x >> 6;
  int lane = threadIdx.x & 63;
  int row = blockIdx.x * 4 + wv;
  int q = row % NQQ;
  const float* hr = h2 + (size_t)row * 256;
  float part[6] = {};
#pragma unroll
  for (int j = 0; j < 4; ++j) {
    float hv = hr[lane + 64 * j];
#pragma unroll
    for (int o = 0; o < 6; ++o)
      part[o] = fmaf(hv, w3[o * 256 + lane + 64 * j], part[o]);
  }
#pragma unroll
  for (int o = 0; o < 6; ++o) part[o] = wred_sum(part[o]);
  if (lane == 0) {
    float prop[6];
#pragma unroll
    for (int o = 0; o < 6; ++o) {
      float v = tanhf(part[o] + b3[o]) * 0.1f + anchors[q * 6 + o];
      prop[o] = fminf(fmaxf(v, 0.f), 1.f);
    }
    float vl0 = prop[0] - 0.5f * prop[3], vh0 = prop[0] + 0.5f * prop[3];
    float vl1 = prop[1] - 0.5f * prop[4], vh1 = prop[1] + 0.5f * prop[4];
    float vl2 = prop[2] - 0.5f * prop[5], vh2 = prop[2] + 0.5f * prop[5];
    int* o = lohi + (size_t)row * 6;
    o[0] = (int)fminf(fmaxf(floorf(vl0 * 20.f - px), 0.f), 20.f);
    o[1] = (int)fminf(fmaxf(floorf(vl1 * 20.f - py), 0.f), 20.f);
    o[2] = (int)fminf(fmaxf(floorf(vl2 * 32.f - pz), 0.f), 32.f);
    o[3] = (int)fminf(fmaxf(floorf(vh0 * 20.f + px), 0.f), 20.f);
    o[4] = (int)fminf(fmaxf(floorf(vh1 * 20.f + py), 0.f), 20.f);
    o[5] = (int)fminf(fmaxf(floorf(vh2 * 32.f + pz), 0.f), 32.f);
  }
}

// ---------------------------------------------------------------------------
extern "C" void kernel_launch(void* const* d_in, const int* in_sizes, int n_in,
                              void* d_out, int out_size, void* d_ws, size_t ws_size,
                              hipStream_t stream)
{
  const float* src       = (const float*)d_in[0];
  const float* pos       = (const float*)d_in[1];
  const float* qe        = (const float*)d_in[2];
  const float* sa_in_w   = (const float*)d_in[3];
  const float* sa_in_b   = (const float*)d_in[4];
  const float* sa_out_w  = (const float*)d_in[5];
  const float* sa_out_b  = (const float*)d_in[6];
  const float* ca_k_w    = (const float*)d_in[7];
  const float* ca_v_w    = (const float*)d_in[8];
  const float* ca_proj_w = (const float*)d_in[9];
  const float* ca_proj_b = (const float*)d_in[10];
  const float* ln1_g = (const float*)d_in[11];
  const float* ln1_b = (const float*)d_in[12];
  const float* ln2_g = (const float*)d_in[13];
  const float* ln2_b = (const float*)d_in[14];
  const float* ln3_g = (const float*)d_in[15];
  const float* ln3_b = (const float*)d_in[16];
  const float* ffn_w1 = (const float*)d_in[17];
  const float* ffn_b1 = (const float*)d_in[18];
  const float* ffn_w2 = (const float*)d_in[19];
  const float* ffn_b2 = (const float*)d_in[20];
  const float* reg_w1 = (const float*)d_in[21];
  const float* reg_b1 = (const float*)d_in[22];
  const float* reg_w2 = (const float*)d_in[23];
  const float* reg_b2 = (const float*)d_in[24];
  const float* reg_w3 = (const float*)d_in[25];
  const float* reg_b3 = (const float*)d_in[26];
  const float* anchors   = (const float*)d_in[27];
  const float* attn_area = (const float*)d_in[28];
  float* outp = (float*)d_out;

  float* ws = (float*)d_ws;
  size_t off = 0;
  auto alloc = [&](size_t n) { float* p = ws + off; off += n; return p; };
  float* Kb   = alloc((size_t)BB * HH * PP * HDIM);  // 26.2 MB
  float* Vb   = alloc((size_t)BB * HH * PP * HDIM);  // 26.2 MB
  float* tgt  = alloc((size_t)MR * DD);
  float* qpos = alloc((size_t)MR * DD);
  float* tmp  = alloc((size_t)MR * DD);
  float* saqk = alloc((size_t)MR * 512);
  float* sav  = alloc((size_t)MR * DD);
  float* sao  = alloc((size_t)MR * DD);
  float* caq  = alloc((size_t)MR * DD);
  float* cao  = alloc((size_t)MR * DD);
  float* mh1  = alloc((size_t)MR * DD);
  float* mh2  = alloc((size_t)MR * DD);
  float* ffh  = alloc((size_t)MR * FFD);
  int*   lohi = (int*)alloc((size_t)MR * 6);
  (void)in_sizes; (void)n_in; (void)out_size; (void)ws_size;

  const float FOCUS_H[6] = {0.1f, 0.075f, 0.05f, 0.05f, 0.025f, 0.025f};

  init_kernel<<<1080, 256, 0, stream>>>(qe, tgt, qpos);

  for (int i = 0; i < LL; ++i) {
    const float* wi  = sa_in_w + (size_t)i * 768 * DD;
    const float* bi  = sa_in_b + (size_t)i * 768;
    // SA: q,k from (tgt+qpos), v from tgt
    gemm_rows<<<dim3(17, 8), 256, 0, stream>>>(tgt, qpos, wi, bi, nullptr, saqk, MR, 512, DD, 0);
    gemm_rows<<<dim3(17, 4), 256, 0, stream>>>(tgt, nullptr, wi + 512 * DD, bi + 512, nullptr, sav, MR, DD, DD, 0);
    sa_attn<<<2160, 256, 0, stream>>>(saqk, sav, sao);
    gemm_rows<<<dim3(17, 4), 256, 0, stream>>>(sao, nullptr, sa_out_w + (size_t)i * DD * DD,
                                               sa_out_b + (size_t)i * DD, tgt, tmp, MR, DD, DD, 0);
    ln_kernel<<<270, 256, 0, stream>>>(tmp, ln2_g + i * DD, ln2_b + i * DD, tgt);

    // mask boxes
    if (i == 0) {
      mask0_kernel<<<5, 256, 0, stream>>>(attn_area, lohi,
          FOCUS_H[0] * PS0, FOCUS_H[0] * PS1, FOCUS_H[0] * PS2);
    } else {
      gemm_rows<<<dim3(17, 4), 256, 0, stream>>>(tgt, nullptr, reg_w1, reg_b1, nullptr, mh1, MR, DD, DD, 1);
      gemm_rows<<<dim3(17, 4), 256, 0, stream>>>(mh1, nullptr, reg_w2, reg_b2, nullptr, mh2, MR, DD, DD, 1);
      mask_reg_kernel<<<270, 256, 0, stream>>>(mh2, reg_w3, reg_b3, anchors, lohi,
          FOCUS_H[i] * PS0, FOCUS_H[i] * PS1, FOCUS_H[i] * PS2);
    }

    // CA: q from (tgt+qpos)@ca_k_w; K from (src+pos)@ca_k_w; V from src@ca_v_w
    gemm_rows<<<dim3(17, 4), 256, 0, stream>>>(tgt, qpos, ca_k_w + (size_t)i * DD * DD,
                                               nullptr, nullptr, caq, MR, DD, DD, 0);
    gemm_kv<<<dim3(200, 4, 2), 256, 0, stream>>>(src, pos, ca_k_w + (size_t)i * DD * DD, Kb);
    gemm_kv<<<dim3(200, 4, 2), 256, 0, stream>>>(src, nullptr, ca_v_w + (size_t)i * DD * DD, Vb);
    ca_attn<<<BB * HH * NQQ, 256, 0, stream>>>(caq, Kb, Vb, lohi, cao);
    gemm_rows<<<dim3(17, 4), 256, 0, stream>>>(cao, nullptr, ca_proj_w + (size_t)i * DD * DD,
                                               ca_proj_b + (size_t)i * DD, tgt, tmp, MR, DD, DD, 0);
    ln_kernel<<<270, 256, 0, stream>>>(tmp, ln1_g + i * DD, ln1_b + i * DD, tgt);

    // FFN
    gemm_rows<<<dim3(17, 16), 256, 0, stream>>>(tgt, nullptr, ffn_w1 + (size_t)i * FFD * DD,
                                                ffn_b1 + (size_t)i * FFD, nullptr, ffh, MR, FFD, DD, 1);
    gemm_rows<<<dim3(17, 4), 256, 0, stream>>>(ffh, nullptr, ffn_w2 + (size_t)i * DD * FFD,
                                               ffn_b2 + (size_t)i * DD, tgt, tmp, MR, DD, FFD, 0);
    float* lno = (i == LL - 1) ? outp : tgt;
    ln_kernel<<<270, 256, 0, stream>>>(tmp, ln3_g + i * DD, ln3_b + i * DD, lno);
  }
}

// Round 4
// 4996.070 us; speedup vs baseline: 1.0795x; 1.0795x over previous
//
#include <hip/hip_runtime.h>
#include <math.h>

#define BB 2
#define DD 256
#define HH 8
#define HDIM 32
#define FFD 1024
#define LL 6
#define NQQ 540
#define QPO_ 27
#define PS0 20
#define PS1 20
#define PS2 32
#define PP (PS0*PS1*PS2)   // 12800
#define MR (BB*NQQ)        // 1080

static __device__ __forceinline__ float wred_sum(float x) {
#pragma unroll
  for (int off = 32; off; off >>= 1) x += __shfl_xor(x, off, 64);
  return x;
}
static __device__ __forceinline__ float wred_max(float x) {
#pragma unroll
  for (int off = 32; off; off >>= 1) x = fmaxf(x, __shfl_xor(x, off, 64));
  return x;
}

// ---------------------------------------------------------------------------
// init: tgt[b,q,d] = qe[q, 256+d]; qpos[b,q,d] = qe[q, d]
__global__ __launch_bounds__(256) void init_kernel(
    const float* __restrict__ qe, float* __restrict__ tgt, float* __restrict__ qpos)
{
  int idx = blockIdx.x * 256 + threadIdx.x;   // < B*NQ*D == 276480
  int d = idx % DD;
  int q = (idx / DD) % NQQ;
  qpos[idx] = qe[q * 512 + d];
  tgt[idx]  = qe[q * 512 + 256 + d];
}

// ---------------------------------------------------------------------------
// Generic row GEMM: C[r,n] = sum_k (A1[r,k] (+A2[r,k])) * W[n,k] (+bias) (+res) (relu?)
// BM=BN=64, BK=16, 256 threads, 4x4 per thread.
__global__ __launch_bounds__(256) void gemm_rows(
    const float* __restrict__ A1, const float* __restrict__ A2,
    const float* __restrict__ W, const float* __restrict__ bias,
    const float* __restrict__ res, float* __restrict__ C,
    int M, int N, int K, int relu)
{
  __shared__ float a_s[16][65];
  __shared__ float w_s[64][17];
  int bm = blockIdx.x * 64;
  int bn = blockIdx.y * 64;
  int t = threadIdx.x;
  int tp = t & 15, to = t >> 4;
  float acc[4][4] = {};
  for (int k0 = 0; k0 < K; k0 += 16) {
    { // A tile: 64 rows x 16 k, one float4 per thread
      int rl = t >> 2;
      int kq = (t & 3) * 4;
      int r = bm + rl;
      float4 av = make_float4(0.f, 0.f, 0.f, 0.f);
      if (r < M) {
        av = *(const float4*)&A1[(size_t)r * K + k0 + kq];
        if (A2) {
          float4 bv = *(const float4*)&A2[(size_t)r * K + k0 + kq];
          av.x += bv.x; av.y += bv.y; av.z += bv.z; av.w += bv.w;
        }
      }
      a_s[kq + 0][rl] = av.x; a_s[kq + 1][rl] = av.y;
      a_s[kq + 2][rl] = av.z; a_s[kq + 3][rl] = av.w;
    }
    { // W tile: 64 n x 16 k
      int ol = t >> 2;
      int kq = (t & 3) * 4;
      float4 wv = *(const float4*)&W[(size_t)(bn + ol) * K + k0 + kq];
      w_s[ol][kq + 0] = wv.x; w_s[ol][kq + 1] = wv.y;
      w_s[ol][kq + 2] = wv.z; w_s[ol][kq + 3] = wv.w;
    }
    __syncthreads();
#pragma unroll
    for (int d = 0; d < 16; ++d) {
      float a[4], w[4];
#pragma unroll
      for (int i = 0; i < 4; ++i) a[i] = a_s[d][tp * 4 + i];
#pragma unroll
      for (int j = 0; j < 4; ++j) w[j] = w_s[to * 4 + j][d];
#pragma unroll
      for (int i = 0; i < 4; ++i)
#pragma unroll
        for (int j = 0; j < 4; ++j)
          acc[i][j] = fmaf(a[i], w[j], acc[i][j]);
    }
    __syncthreads();
  }
#pragma unroll
  for (int i = 0; i < 4; ++i) {
    int r = bm + tp * 4 + i;
    if (r >= M) continue;
#pragma unroll
    for (int j = 0; j < 4; ++j) {
      int n = bn + to * 4 + j;
      float v = acc[i][j];
      if (bias) v += bias[n];
      if (relu) v = fmaxf(v, 0.f);
      if (res)  v += res[(size_t)r * N + n];
      C[(size_t)r * N + n] = v;
    }
  }
}

// ---------------------------------------------------------------------------
// K/V projection GEMM. A(r=p, k=d) = src[b,d,p] (+pos[b,d,p]); W (256,256) row-major (o,d).
// Output layout: out[b][h][p][hd], n = h*32+hd.
__global__ __launch_bounds__(256) void gemm_kv(
    const float* __restrict__ src, const float* __restrict__ pos,
    const float* __restrict__ W, float* __restrict__ out)
{
  __shared__ float a_s[16][65];
  __shared__ float w_s[64][17];
  int b = blockIdx.z;
  int p0 = blockIdx.x * 64;
  int n0 = blockIdx.y * 64;
  int t = threadIdx.x;
  int tp = t & 15, to = t >> 4;
  const float* sb = src + (size_t)b * DD * PP;
  const float* pb = pos ? pos + (size_t)b * DD * PP : nullptr;
  float acc[4][4] = {};
  for (int k0 = 0; k0 < DD; k0 += 16) {
    { // A tile: a_s[dl][pl] = src[b][k0+dl][p0+pl] (+pos). contiguous in p -> coalesced
      int dl = t >> 4;
      int pq = (t & 15) * 4;
      float4 av = *(const float4*)&sb[(size_t)(k0 + dl) * PP + p0 + pq];
      if (pb) {
        float4 pv = *(const float4*)&pb[(size_t)(k0 + dl) * PP + p0 + pq];
        av.x += pv.x; av.y += pv.y; av.z += pv.z; av.w += pv.w;
      }
      a_s[dl][pq + 0] = av.x; a_s[dl][pq + 1] = av.y;
      a_s[dl][pq + 2] = av.z; a_s[dl][pq + 3] = av.w;
    }
    {
      int ol = t >> 2;
      int kq = (t & 3) * 4;
      float4 wv = *(const float4*)&W[(size_t)(n0 + ol) * DD + k0 + kq];
      w_s[ol][kq + 0] = wv.x; w_s[ol][kq + 1] = wv.y;
      w_s[ol][kq + 2] = wv.z; w_s[ol][kq + 3] = wv.w;
    }
    __syncthreads();
#pragma unroll
    for (int d = 0; d < 16; ++d) {
      float a[4], w[4];
#pragma unroll
      for (int i = 0; i < 4; ++i) a[i] = a_s[d][tp * 4 + i];
#pragma unroll
      for (int j = 0; j < 4; ++j) w[j] = w_s[to * 4 + j][d];
#pragma unroll
      for (int i = 0; i < 4; ++i)
#pragma unroll
        for (int j = 0; j < 4; ++j)
          acc[i][j] = fmaf(a[i], w[j], acc[i][j]);
    }
    __syncthreads();
  }
#pragma unroll
  for (int i = 0; i < 4; ++i) {
    int p = p0 + tp * 4 + i;
#pragma unroll
    for (int j = 0; j < 4; ++j) {
      int n = n0 + to * 4 + j;
      int h = n >> 5, hd = n & 31;
      out[((size_t)(b * HH + h) * PP + p) * HDIM + hd] = acc[i][j];
    }
  }
}

// ---------------------------------------------------------------------------
// Self-attention: one wave per (b,h,q), 540 keys, no mask.
// qkbuf: (MR,512) q cols 0..255, k cols 256..511. vbuf: (MR,256). out: (MR,256).
__global__ __launch_bounds__(256) void sa_attn(
    const float* __restrict__ qkbuf, const float* __restrict__ vbuf,
    float* __restrict__ out)
{
  __shared__ float plds[4][NQQ];
  int wv = threadIdx.x >> 6;
  int lane = threadIdx.x & 63;
  int wid = blockIdx.x * 4 + wv;
  int q = wid % NQQ;
  int h = (wid / NQQ) % HH;
  int b = wid / (NQQ * HH);
  const float scale = 0.17677669529663687f;  // 32^-0.5

  const float* qp = qkbuf + (size_t)(b * NQQ + q) * 512 + h * 32;
  float4 q4[8];
#pragma unroll
  for (int u = 0; u < 8; ++u) q4[u] = ((const float4*)qp)[u];

  const float* kb = qkbuf + (size_t)b * NQQ * 512 + 256 + h * 32;
  float lg[9];
  float mx = -INFINITY;
#pragma unroll
  for (int j = 0; j < 9; ++j) {
    int k = lane + j * 64;
    float s = -INFINITY;
    if (k < NQQ) {
      const float4* kp = (const float4*)(kb + (size_t)k * 512);
      float acc = 0.f;
#pragma unroll
      for (int u = 0; u < 8; ++u) {
        float4 kv4 = kp[u];
        acc = fmaf(q4[u].x, kv4.x, acc);
        acc = fmaf(q4[u].y, kv4.y, acc);
        acc = fmaf(q4[u].z, kv4.z, acc);
        acc = fmaf(q4[u].w, kv4.w, acc);
      }
      s = acc * scale;
    }
    lg[j] = s;
    mx = fmaxf(mx, s);
  }
  mx = wred_max(mx);
  float ssum = 0.f;
#pragma unroll
  for (int j = 0; j < 9; ++j) {
    int k = lane + j * 64;
    if (k < NQQ) {
      float p = __expf(lg[j] - mx);
      plds[wv][k] = p;
      ssum += p;
    }
  }
  ssum = wred_sum(ssum);

  int dow = lane & 31, half = lane >> 5;
  const float* vb = vbuf + (size_t)b * NQQ * 256 + h * 32 + dow;
  float oa0 = 0.f, oa1 = 0.f, oa2 = 0.f, oa3 = 0.f;
  int k = half;
  for (; k + 6 < NQQ; k += 8) {
    float p0 = plds[wv][k],     p1 = plds[wv][k + 2];
    float p2 = plds[wv][k + 4], p3 = plds[wv][k + 6];
    oa0 = fmaf(p0, vb[(size_t)k * 256],       oa0);
    oa1 = fmaf(p1, vb[(size_t)(k + 2) * 256], oa1);
    oa2 = fmaf(p2, vb[(size_t)(k + 4) * 256], oa2);
    oa3 = fmaf(p3, vb[(size_t)(k + 6) * 256], oa3);
  }
  for (; k < NQQ; k += 2)
    oa0 = fmaf(plds[wv][k], vb[(size_t)k * 256], oa0);
  float oa = (oa0 + oa1) + (oa2 + oa3);
  oa += __shfl_xor(oa, 32, 64);
  if (lane < 32)
    out[(size_t)(b * NQQ + q) * 256 + h * 32 + lane] = oa / ssum;
}

// ---------------------------------------------------------------------------
// Cross-attention with box mask. One BLOCK (4 waves) per (b,h,q).
// R1 structure (per-lane K scatter + shfl-broadcast coalesced PV) with:
//  - branch-free key loop (clamped indices, -inf logits for tail lanes)
//  - software-pipelined K loads: next tile's 8 float4 loads issue before
//    the current tile's softmax/PV work, hiding L2/HBM latency in-wave.
// qbuf: (MR,256). Kbuf/Vbuf: [b][h][p][hd]. lohi: (MR,6).
__global__ __launch_bounds__(256) void ca_attn(
    const float* __restrict__ qbuf, const float* __restrict__ Kbuf,
    const float* __restrict__ Vbuf, const int* __restrict__ lohi,
    float* __restrict__ out)
{
  __shared__ float cm[4], cs[4], co[4][32];
  int wv = threadIdx.x >> 6;
  int lane = threadIdx.x & 63;
  int wid = blockIdx.x;
  int q = wid % NQQ;
  int h = (wid / NQQ) % HH;
  int b = wid / (NQQ * HH);
  const float scale = 0.17677669529663687f;

  const int* lh = lohi + (size_t)(b * NQQ + q) * 6;
  int lo0 = lh[0], lo1 = lh[1], lo2 = lh[2];
  int nx = lh[3] - lo0, ny = lh[4] - lo1, nz = lh[5] - lo2;
  int nyz = ny * nz;
  int nk = nx * nyz;

  const float* qp = qbuf + (size_t)(b * NQQ + q) * 256 + h * 32;
  float4 q4[8];
#pragma unroll
  for (int u = 0; u < 8; ++u) q4[u] = ((const float4*)qp)[u];

  const float* Kb = Kbuf + (size_t)(b * HH + h) * PP * HDIM;
  const float* Vb = Vbuf + (size_t)(b * HH + h) * PP * HDIM;
  int dow = lane & 31, half = lane >> 5;
  float m = -INFINITY, sl = 0.f;
  float oa0 = 0.f, oa1 = 0.f, oa2 = 0.f, oa3 = 0.f;

  if (nk > 0) {
    float inv_nyz = 1.0f / (float)nyz;
    float inv_nz  = 1.0f / (float)nz;
    // decompose clamped linear box index -> grid pidx (float-recip div + fixup)
    auto decomp = [&](int tt) {
      int x = (int)((float)tt * inv_nyz);
      int r = tt - x * nyz;
      if (r < 0)         { x--; r += nyz; }
      else if (r >= nyz) { x++; r -= nyz; }
      int y = (int)((float)r * inv_nz);
      int z = r - y * nz;
      if (z < 0)         { y--; z += nz; }
      else if (z >= nz)  { y++; z -= nz; }
      return (lo0 + x) * (PS1 * PS2) + (lo1 + y) * PS2 + (lo2 + z);
    };

    int t = wv * 64 + lane;
    int tc = t < nk ? t : nk - 1;
    int pidx = decomp(tc);
    const float4* kp0 = (const float4*)(Kb + (size_t)pidx * HDIM);
    float4 kv0 = kp0[0], kv1 = kp0[1], kv2 = kp0[2], kv3 = kp0[3];
    float4 kv4 = kp0[4], kv5 = kp0[5], kv6 = kp0[6], kv7 = kp0[7];

    for (int t0 = wv * 64; t0 < nk; t0 += 256) {
      // --- next-tile index + K prefetch (issues before current compute) ---
      int tn = t0 + 256 + lane;
      int tcn = tn < nk ? tn : nk - 1;
      int pidx_n = decomp(tcn);
      const float4* kpn = (const float4*)(Kb + (size_t)pidx_n * HDIM);
      float4 kn0 = kpn[0], kn1 = kpn[1], kn2 = kpn[2], kn3 = kpn[3];
      float4 kn4 = kpn[4], kn5 = kpn[5], kn6 = kpn[6], kn7 = kpn[7];

      // --- current tile: QK dot ---
      float acc = 0.f;
      acc = fmaf(q4[0].x, kv0.x, acc); acc = fmaf(q4[0].y, kv0.y, acc);
      acc = fmaf(q4[0].z, kv0.z, acc); acc = fmaf(q4[0].w, kv0.w, acc);
      acc = fmaf(q4[1].x, kv1.x, acc); acc = fmaf(q4[1].y, kv1.y, acc);
      acc = fmaf(q4[1].z, kv1.z, acc); acc = fmaf(q4[1].w, kv1.w, acc);
      acc = fmaf(q4[2].x, kv2.x, acc); acc = fmaf(q4[2].y, kv2.y, acc);
      acc = fmaf(q4[2].z, kv2.z, acc); acc = fmaf(q4[2].w, kv2.w, acc);
      acc = fmaf(q4[3].x, kv3.x, acc); acc = fmaf(q4[3].y, kv3.y, acc);
      acc = fmaf(q4[3].z, kv3.z, acc); acc = fmaf(q4[3].w, kv3.w, acc);
      acc = fmaf(q4[4].x, kv4.x, acc); acc = fmaf(q4[4].y, kv4.y, acc);
      acc = fmaf(q4[4].z, kv4.z, acc); acc = fmaf(q4[4].w, kv4.w, acc);
      acc = fmaf(q4[5].x, kv5.x, acc); acc = fmaf(q4[5].y, kv5.y, acc);
      acc = fmaf(q4[5].z, kv5.z, acc); acc = fmaf(q4[5].w, kv5.w, acc);
      acc = fmaf(q4[6].x, kv6.x, acc); acc = fmaf(q4[6].y, kv6.y, acc);
      acc = fmaf(q4[6].z, kv6.z, acc); acc = fmaf(q4[6].w, kv6.w, acc);
      acc = fmaf(q4[7].x, kv7.x, acc); acc = fmaf(q4[7].y, kv7.y, acc);
      acc = fmaf(q4[7].z, kv7.z, acc); acc = fmaf(q4[7].w, kv7.w, acc);
      int t_cur = t0 + lane;
      float lg = (t_cur < nk) ? acc * scale : -INFINITY;

      // --- online softmax ---
      float mn = fmaxf(m, wred_max(lg));
      float f = __expf(m - mn);
      oa0 *= f; oa1 *= f; oa2 *= f; oa3 *= f; sl *= f;
      float p = __expf(lg - mn);        // -inf -> 0 pads tail lanes
      sl += p;
      m = mn;

      // --- PV: broadcast p/pidx via shfl; coalesced V reads ---
#pragma unroll
      for (int g = 0; g < 8; ++g) {
        int kb_ = half + 8 * g;
        float p0 = __shfl(p, kb_,     64); int i0 = __shfl(pidx, kb_,     64);
        float p1 = __shfl(p, kb_ + 2, 64); int i1 = __shfl(pidx, kb_ + 2, 64);
        float p2 = __shfl(p, kb_ + 4, 64); int i2 = __shfl(pidx, kb_ + 4, 64);
        float p3 = __shfl(p, kb_ + 6, 64); int i3 = __shfl(pidx, kb_ + 6, 64);
        oa0 = fmaf(p0, Vb[(size_t)i0 * HDIM + dow], oa0);
        oa1 = fmaf(p1, Vb[(size_t)i1 * HDIM + dow], oa1);
        oa2 = fmaf(p2, Vb[(size_t)i2 * HDIM + dow], oa2);
        oa3 = fmaf(p3, Vb[(size_t)i3 * HDIM + dow], oa3);
      }

      // --- rotate double buffer ---
      kv0 = kn0; kv1 = kn1; kv2 = kn2; kv3 = kn3;
      kv4 = kn4; kv5 = kn5; kv6 = kn6; kv7 = kn7;
      pidx = pidx_n;
    }
  }

  // ---- merge the 4 wave-states ----
  float oa = (oa0 + oa1) + (oa2 + oa3);
  oa += __shfl_xor(oa, 32, 64);        // sum the two half-lane partials
  float slt = wred_sum(sl);
  if (lane == 0) { cm[wv] = m; cs[wv] = slt; }
  if (lane < 32) co[wv][lane] = oa;
  __syncthreads();
  if (threadIdx.x < 32) {
    float M = fmaxf(fmaxf(cm[0], cm[1]), fmaxf(cm[2], cm[3]));
    float num = 0.f, den = 0.f;
#pragma unroll
    for (int w = 0; w < 4; ++w) {
      float fw = __expf(cm[w] - M);    // empty-wave m=-inf -> fw=0
      den = fmaf(fw, cs[w], den);
      num = fmaf(fw, co[w][threadIdx.x], num);
    }
    out[(size_t)(b * NQQ + q) * 256 + h * 32 + threadIdx.x] = num / den;
  }
}

// ---------------------------------------------------------------------------
// LayerNorm over D=256: one wave per row. x already contains residual sum.
__global__ __launch_bounds__(256) void ln_kernel(
    const float* __restrict__ x, const float* __restrict__ g,
    const float* __restrict__ bta, float* __restrict__ out)
{
  int wv = threadIdx.x >> 6;
  int lane = threadIdx.x & 63;
  int row = blockIdx.x * 4 + wv;
  const float* xr = x + (size_t)row * 256;
  float v[4];
#pragma unroll
  for (int j = 0; j < 4; ++j) v[j] = xr[lane + 64 * j];
  float s = v[0] + v[1] + v[2] + v[3];
  s = wred_sum(s);
  float mean = s * (1.f / 256.f);
  float vs = 0.f;
#pragma unroll
  for (int j = 0; j < 4; ++j) { float d = v[j] - mean; vs = fmaf(d, d, vs); }
  vs = wred_sum(vs);
  float inv = rsqrtf(vs * (1.f / 256.f) + 1e-5f);
  float* orow = out + (size_t)row * 256;
#pragma unroll
  for (int j = 0; j < 4; ++j) {
    int c = lane + 64 * j;
    orow[c] = (v[j] - mean) * inv * g[c] + bta[c];
  }
}

// ---------------------------------------------------------------------------
// Layer-0 mask boxes from attn_area.
__global__ __launch_bounds__(256) void mask0_kernel(
    const float* __restrict__ area, int* __restrict__ lohi,
    float px, float py, float pz)
{
  int row = blockIdx.x * 256 + threadIdx.x;
  if (row >= MR) return;
  int q = row % NQQ;
  int org = q / QPO_;
  const float* a = area + org * 6;
  int* o = lohi + (size_t)row * 6;
  o[0] = (int)fminf(fmaxf(floorf(a[0] * 20.f - px), 0.f), 20.f);
  o[1] = (int)fminf(fmaxf(floorf(a[1] * 20.f - py), 0.f), 20.f);
  o[2] = (int)fminf(fmaxf(floorf(a[2] * 32.f - pz), 0.f), 32.f);
  o[3] = (int)fminf(fmaxf(floorf(a[3] * 20.f + px), 0.f), 20.f);
  o[4] = (int)fminf(fmaxf(floorf(a[4] * 20.f + py), 0.f), 20.f);
  o[5] = (int)fminf(fmaxf(floorf(a[5] * 32.f + pz), 0.f), 32.f);
}

// ---------------------------------------------------------------------------
// Layers >=1: prop = h2 @ w3.T + b3 -> tanh*0.1 + anchors -> clip -> box ints.
// One wave per (b,q) row.
__global__ __launch_bounds__(256) void mask_reg_kernel(
    const float* __restrict__ h2, const float* __restrict__ w3,
    const float* __restrict__ b3, const float* __restrict__ anchors,
    int* __restrict__ lohi, float px, float py, float pz)
{
  int wv = threadIdx.x >> 6;
  int lane = threadIdx.x & 63;
  int row = blockIdx.x * 4 + wv;
  int q = row % NQQ;
  const float* hr = h2 + (size_t)row * 256;
  float part[6] = {};
#pragma unroll
  for (int j = 0; j < 4; ++j) {
    float hv = hr[lane + 64 * j];
#pragma unroll
    for (int o = 0; o < 6; ++o)
      part[o] = fmaf(hv, w3[o * 256 + lane + 64 * j], part[o]);
  }
#pragma unroll
  for (int o = 0; o < 6; ++o) part[o] = wred_sum(part[o]);
  if (lane == 0) {
    float prop[6];
#pragma unroll
    for (int o = 0; o < 6; ++o) {
      float v = tanhf(part[o] + b3[o]) * 0.1f + anchors[q * 6 + o];
      prop[o] = fminf(fmaxf(v, 0.f), 1.f);
    }
    float vl0 = prop[0] - 0.5f * prop[3], vh0 = prop[0] + 0.5f * prop[3];
    float vl1 = prop[1] - 0.5f * prop[4], vh1 = prop[1] + 0.5f * prop[4];
    float vl2 = prop[2] - 0.5f * prop[5], vh2 = prop[2] + 0.5f * prop[5];
    int* o = lohi + (size_t)row * 6;
    o[0] = (int)fminf(fmaxf(floorf(vl0 * 20.f - px), 0.f), 20.f);
    o[1] = (int)fminf(fmaxf(floorf(vl1 * 20.f - py), 0.f), 20.f);
    o[2] = (int)fminf(fmaxf(floorf(vl2 * 32.f - pz), 0.f), 32.f);
    o[3] = (int)fminf(fmaxf(floorf(vh0 * 20.f + px), 0.f), 20.f);
    o[4] = (int)fminf(fmaxf(floorf(vh1 * 20.f + py), 0.f), 20.f);
    o[5] = (int)fminf(fmaxf(floorf(vh2 * 32.f + pz), 0.f), 32.f);
  }
}

// ---------------------------------------------------------------------------
extern "C" void kernel_launch(void* const* d_in, const int* in_sizes, int n_in,
                              void* d_out, int out_size, void* d_ws, size_t ws_size,
                              hipStream_t stream)
{
  const float* src       = (const float*)d_in[0];
  const float* pos       = (const float*)d_in[1];
  const float* qe        = (const float*)d_in[2];
  const float* sa_in_w   = (const float*)d_in[3];
  const float* sa_in_b   = (const float*)d_in[4];
  const float* sa_out_w  = (const float*)d_in[5];
  const float* sa_out_b  = (const float*)d_in[6];
  const float* ca_k_w    = (const float*)d_in[7];
  const float* ca_v_w    = (const float*)d_in[8];
  const float* ca_proj_w = (const float*)d_in[9];
  const float* ca_proj_b = (const float*)d_in[10];
  const float* ln1_g = (const float*)d_in[11];
  const float* ln1_b = (const float*)d_in[12];
  const float* ln2_g = (const float*)d_in[13];
  const float* ln2_b = (const float*)d_in[14];
  const float* ln3_g = (const float*)d_in[15];
  const float* ln3_b = (const float*)d_in[16];
  const float* ffn_w1 = (const float*)d_in[17];
  const float* ffn_b1 = (const float*)d_in[18];
  const float* ffn_w2 = (const float*)d_in[19];
  const float* ffn_b2 = (const float*)d_in[20];
  const float* reg_w1 = (const float*)d_in[21];
  const float* reg_b1 = (const float*)d_in[22];
  const float* reg_w2 = (const float*)d_in[23];
  const float* reg_b2 = (const float*)d_in[24];
  const float* reg_w3 = (const float*)d_in[25];
  const float* reg_b3 = (const float*)d_in[26];
  const float* anchors   = (const float*)d_in[27];
  const float* attn_area = (const float*)d_in[28];
  float* outp = (float*)d_out;

  float* ws = (float*)d_ws;
  size_t off = 0;
  auto alloc = [&](size_t n) { float* p = ws + off; off += n; return p; };
  float* Kb   = alloc((size_t)BB * HH * PP * HDIM);  // 26.2 MB
  float* Vb   = alloc((size_t)BB * HH * PP * HDIM);  // 26.2 MB
  float* tgt  = alloc((size_t)MR * DD);
  float* qpos = alloc((size_t)MR * DD);
  float* tmp  = alloc((size_t)MR * DD);
  float* saqk = alloc((size_t)MR * 512);
  float* sav  = alloc((size_t)MR * DD);
  float* sao  = alloc((size_t)MR * DD);
  float* caq  = alloc((size_t)MR * DD);
  float* cao  = alloc((size_t)MR * DD);
  float* mh1  = alloc((size_t)MR * DD);
  float* mh2  = alloc((size_t)MR * DD);
  float* ffh  = alloc((size_t)MR * FFD);
  int*   lohi = (int*)alloc((size_t)MR * 6);
  (void)in_sizes; (void)n_in; (void)out_size; (void)ws_size;

  const float FOCUS_H[6] = {0.1f, 0.075f, 0.05f, 0.05f, 0.025f, 0.025f};

  init_kernel<<<1080, 256, 0, stream>>>(qe, tgt, qpos);

  for (int i = 0; i < LL; ++i) {
    const float* wi  = sa_in_w + (size_t)i * 768 * DD;
    const float* bi  = sa_in_b + (size_t)i * 768;
    // SA: q,k from (tgt+qpos), v from tgt
    gemm_rows<<<dim3(17, 8), 256, 0, stream>>>(tgt, qpos, wi, bi, nullptr, saqk, MR, 512, DD, 0);
    gemm_rows<<<dim3(17, 4), 256, 0, stream>>>(tgt, nullptr, wi + 512 * DD, bi + 512, nullptr, sav, MR, DD, DD, 0);
    sa_attn<<<2160, 256, 0, stream>>>(saqk, sav, sao);
    gemm_rows<<<dim3(17, 4), 256, 0, stream>>>(sao, nullptr, sa_out_w + (size_t)i * DD * DD,
                                               sa_out_b + (size_t)i * DD, tgt, tmp, MR, DD, DD, 0);
    ln_kernel<<<270, 256, 0, stream>>>(tmp, ln2_g + i * DD, ln2_b + i * DD, tgt);

    // mask boxes
    if (i == 0) {
      mask0_kernel<<<5, 256, 0, stream>>>(attn_area, lohi,
          FOCUS_H[0] * PS0, FOCUS_H[0] * PS1, FOCUS_H[0] * PS2);
    } else {
      gemm_rows<<<dim3(17, 4), 256, 0, stream>>>(tgt, nullptr, reg_w1, reg_b1, nullptr, mh1, MR, DD, DD, 1);
      gemm_rows<<<dim3(17, 4), 256, 0, stream>>>(mh1, nullptr, reg_w2, reg_b2, nullptr, mh2, MR, DD, DD, 1);
      mask_reg_kernel<<<270, 256, 0, stream>>>(mh2, reg_w3, reg_b3, anchors, lohi,
          FOCUS_H[i] * PS0, FOCUS_H[i] * PS1, FOCUS_H[i] * PS2);
    }

    // CA: q from (tgt+qpos)@ca_k_w; K from (src+pos)@ca_k_w; V from src@ca_v_w
    gemm_rows<<<dim3(17, 4), 256, 0, stream>>>(tgt, qpos, ca_k_w + (size_t)i * DD * DD,
                                               nullptr, nullptr, caq, MR, DD, DD, 0);
    gemm_kv<<<dim3(200, 4, 2), 256, 0, stream>>>(src, pos, ca_k_w + (size_t)i * DD * DD, Kb);
    gemm_kv<<<dim3(200, 4, 2), 256, 0, stream>>>(src, nullptr, ca_v_w + (size_t)i * DD * DD, Vb);
    ca_attn<<<BB * HH * NQQ, 256, 0, stream>>>(caq, Kb, Vb, lohi, cao);
    gemm_rows<<<dim3(17, 4), 256, 0, stream>>>(cao, nullptr, ca_proj_w + (size_t)i * DD * DD,
                                               ca_proj_b + (size_t)i * DD, tgt, tmp, MR, DD, DD, 0);
    ln_kernel<<<270, 256, 0, stream>>>(tmp, ln1_g + i * DD, ln1_b + i * DD, tgt);

    // FFN
    gemm_rows<<<dim3(17, 16), 256, 0, stream>>>(tgt, nullptr, ffn_w1 + (size_t)i * FFD * DD,
                                                ffn_b1 + (size_t)i * FFD, nullptr, ffh, MR, FFD, DD, 1);
    gemm_rows<<<dim3(17, 4), 256, 0, stream>>>(ffh, nullptr, ffn_w2 + (size_t)i * DD * FFD,
                                               ffn_b2 + (size_t)i * DD, tgt, tmp, MR, DD, FFD, 0);
    float* lno = (i == LL - 1) ? outp : tgt;
    ln_kernel<<<270, 256, 0, stream>>>(tmp, ln3_g + i * DD, ln3_b + i * DD, lno);
  }
}

// Round 5
// 4912.297 us; speedup vs baseline: 1.0979x; 1.0171x over previous
//
#include <hip/hip_runtime.h>
#include <math.h>

#define BB 2
#define DD 256
#define HH 8
#define HDIM 32
#define FFD 1024
#define LL 6
#define NQQ 540
#define QPO_ 27
#define PS0 20
#define PS1 20
#define PS2 32
#define PP (PS0*PS1*PS2)   // 12800
#define MR (BB*NQQ)        // 1080

static __device__ __forceinline__ float wred_sum(float x) {
#pragma unroll
  for (int off = 32; off; off >>= 1) x += __shfl_xor(x, off, 64);
  return x;
}
static __device__ __forceinline__ float wred_max(float x) {
#pragma unroll
  for (int off = 32; off; off >>= 1) x = fmaxf(x, __shfl_xor(x, off, 64));
  return x;
}

// ---------------------------------------------------------------------------
// init: tgt[b,q,d] = qe[q, 256+d]; qpos[b,q,d] = qe[q, d]
__global__ __launch_bounds__(256) void init_kernel(
    const float* __restrict__ qe, float* __restrict__ tgt, float* __restrict__ qpos)
{
  int idx = blockIdx.x * 256 + threadIdx.x;   // < B*NQ*D == 276480
  int d = idx % DD;
  int q = (idx / DD) % NQQ;
  qpos[idx] = qe[q * 512 + d];
  tgt[idx]  = qe[q * 512 + 256 + d];
}

// ---------------------------------------------------------------------------
// Generic row GEMM: C[r,n] = sum_k (A1[r,k] (+A2[r,k])) * W[n,k] (+bias) (+res) (relu?)
// BM=BN=64, BK=16, 256 threads, 4x4 per thread.
__global__ __launch_bounds__(256) void gemm_rows(
    const float* __restrict__ A1, const float* __restrict__ A2,
    const float* __restrict__ W, const float* __restrict__ bias,
    const float* __restrict__ res, float* __restrict__ C,
    int M, int N, int K, int relu)
{
  __shared__ float a_s[16][65];
  __shared__ float w_s[64][17];
  int bm = blockIdx.x * 64;
  int bn = blockIdx.y * 64;
  int t = threadIdx.x;
  int tp = t & 15, to = t >> 4;
  float acc[4][4] = {};
  for (int k0 = 0; k0 < K; k0 += 16) {
    { // A tile: 64 rows x 16 k, one float4 per thread
      int rl = t >> 2;
      int kq = (t & 3) * 4;
      int r = bm + rl;
      float4 av = make_float4(0.f, 0.f, 0.f, 0.f);
      if (r < M) {
        av = *(const float4*)&A1[(size_t)r * K + k0 + kq];
        if (A2) {
          float4 bv = *(const float4*)&A2[(size_t)r * K + k0 + kq];
          av.x += bv.x; av.y += bv.y; av.z += bv.z; av.w += bv.w;
        }
      }
      a_s[kq + 0][rl] = av.x; a_s[kq + 1][rl] = av.y;
      a_s[kq + 2][rl] = av.z; a_s[kq + 3][rl] = av.w;
    }
    { // W tile: 64 n x 16 k
      int ol = t >> 2;
      int kq = (t & 3) * 4;
      float4 wv = *(const float4*)&W[(size_t)(bn + ol) * K + k0 + kq];
      w_s[ol][kq + 0] = wv.x; w_s[ol][kq + 1] = wv.y;
      w_s[ol][kq + 2] = wv.z; w_s[ol][kq + 3] = wv.w;
    }
    __syncthreads();
#pragma unroll
    for (int d = 0; d < 16; ++d) {
      float a[4], w[4];
#pragma unroll
      for (int i = 0; i < 4; ++i) a[i] = a_s[d][tp * 4 + i];
#pragma unroll
      for (int j = 0; j < 4; ++j) w[j] = w_s[to * 4 + j][d];
#pragma unroll
      for (int i = 0; i < 4; ++i)
#pragma unroll
        for (int j = 0; j < 4; ++j)
          acc[i][j] = fmaf(a[i], w[j], acc[i][j]);
    }
    __syncthreads();
  }
#pragma unroll
  for (int i = 0; i < 4; ++i) {
    int r = bm + tp * 4 + i;
    if (r >= M) continue;
#pragma unroll
    for (int j = 0; j < 4; ++j) {
      int n = bn + to * 4 + j;
      float v = acc[i][j];
      if (bias) v += bias[n];
      if (relu) v = fmaxf(v, 0.f);
      if (res)  v += res[(size_t)r * N + n];
      C[(size_t)r * N + n] = v;
    }
  }
}

// ---------------------------------------------------------------------------
// K/V projection GEMM. A(r=p, k=d) = src[b,d,p] (+pos[b,d,p]); W (256,256) row-major (o,d).
// Output layout: out[b][p][n] (n = h*32+hd contiguous per key) -> float4 stores.
__global__ __launch_bounds__(256) void gemm_kv(
    const float* __restrict__ src, const float* __restrict__ pos,
    const float* __restrict__ W, float* __restrict__ out)
{
  __shared__ float a_s[16][65];
  __shared__ float w_s[64][17];
  int b = blockIdx.z;
  int p0 = blockIdx.x * 64;
  int n0 = blockIdx.y * 64;
  int t = threadIdx.x;
  int tp = t & 15, to = t >> 4;
  const float* sb = src + (size_t)b * DD * PP;
  const float* pb = pos ? pos + (size_t)b * DD * PP : nullptr;
  float acc[4][4] = {};
  for (int k0 = 0; k0 < DD; k0 += 16) {
    { // A tile: a_s[dl][pl] = src[b][k0+dl][p0+pl] (+pos). contiguous in p -> coalesced
      int dl = t >> 4;
      int pq = (t & 15) * 4;
      float4 av = *(const float4*)&sb[(size_t)(k0 + dl) * PP + p0 + pq];
      if (pb) {
        float4 pv = *(const float4*)&pb[(size_t)(k0 + dl) * PP + p0 + pq];
        av.x += pv.x; av.y += pv.y; av.z += pv.z; av.w += pv.w;
      }
      a_s[dl][pq + 0] = av.x; a_s[dl][pq + 1] = av.y;
      a_s[dl][pq + 2] = av.z; a_s[dl][pq + 3] = av.w;
    }
    {
      int ol = t >> 2;
      int kq = (t & 3) * 4;
      float4 wv = *(const float4*)&W[(size_t)(n0 + ol) * DD + k0 + kq];
      w_s[ol][kq + 0] = wv.x; w_s[ol][kq + 1] = wv.y;
      w_s[ol][kq + 2] = wv.z; w_s[ol][kq + 3] = wv.w;
    }
    __syncthreads();
#pragma unroll
    for (int d = 0; d < 16; ++d) {
      float a[4], w[4];
#pragma unroll
      for (int i = 0; i < 4; ++i) a[i] = a_s[d][tp * 4 + i];
#pragma unroll
      for (int j = 0; j < 4; ++j) w[j] = w_s[to * 4 + j][d];
#pragma unroll
      for (int i = 0; i < 4; ++i)
#pragma unroll
        for (int j = 0; j < 4; ++j)
          acc[i][j] = fmaf(a[i], w[j], acc[i][j]);
    }
    __syncthreads();
  }
#pragma unroll
  for (int i = 0; i < 4; ++i) {
    int p = p0 + tp * 4 + i;
    float4 v = make_float4(acc[i][0], acc[i][1], acc[i][2], acc[i][3]);
    *(float4*)&out[((size_t)b * PP + p) * 256 + n0 + to * 4] = v;
  }
}

// ---------------------------------------------------------------------------
// Self-attention: one wave per (b,h,q), 540 keys, no mask.
// qkbuf: (MR,512) q cols 0..255, k cols 256..511. vbuf: (MR,256). out: (MR,256).
__global__ __launch_bounds__(256) void sa_attn(
    const float* __restrict__ qkbuf, const float* __restrict__ vbuf,
    float* __restrict__ out)
{
  __shared__ float plds[4][NQQ];
  int wv = threadIdx.x >> 6;
  int lane = threadIdx.x & 63;
  int wid = blockIdx.x * 4 + wv;
  int q = wid % NQQ;
  int h = (wid / NQQ) % HH;
  int b = wid / (NQQ * HH);
  const float scale = 0.17677669529663687f;  // 32^-0.5

  const float* qp = qkbuf + (size_t)(b * NQQ + q) * 512 + h * 32;
  float4 q4[8];
#pragma unroll
  for (int u = 0; u < 8; ++u) q4[u] = ((const float4*)qp)[u];

  const float* kb = qkbuf + (size_t)b * NQQ * 512 + 256 + h * 32;
  float lg[9];
  float mx = -INFINITY;
#pragma unroll
  for (int j = 0; j < 9; ++j) {
    int k = lane + j * 64;
    float s = -INFINITY;
    if (k < NQQ) {
      const float4* kp = (const float4*)(kb + (size_t)k * 512);
      float acc = 0.f;
#pragma unroll
      for (int u = 0; u < 8; ++u) {
        float4 kv4 = kp[u];
        acc = fmaf(q4[u].x, kv4.x, acc);
        acc = fmaf(q4[u].y, kv4.y, acc);
        acc = fmaf(q4[u].z, kv4.z, acc);
        acc = fmaf(q4[u].w, kv4.w, acc);
      }
      s = acc * scale;
    }
    lg[j] = s;
    mx = fmaxf(mx, s);
  }
  mx = wred_max(mx);
  float ssum = 0.f;
#pragma unroll
  for (int j = 0; j < 9; ++j) {
    int k = lane + j * 64;
    if (k < NQQ) {
      float p = __expf(lg[j] - mx);
      plds[wv][k] = p;
      ssum += p;
    }
  }
  ssum = wred_sum(ssum);

  int dow = lane & 31, half = lane >> 5;
  const float* vb = vbuf + (size_t)b * NQQ * 256 + h * 32 + dow;
  float oa0 = 0.f, oa1 = 0.f, oa2 = 0.f, oa3 = 0.f;
  int k = half;
  for (; k + 6 < NQQ; k += 8) {
    float p0 = plds[wv][k],     p1 = plds[wv][k + 2];
    float p2 = plds[wv][k + 4], p3 = plds[wv][k + 6];
    oa0 = fmaf(p0, vb[(size_t)k * 256],       oa0);
    oa1 = fmaf(p1, vb[(size_t)(k + 2) * 256], oa1);
    oa2 = fmaf(p2, vb[(size_t)(k + 4) * 256], oa2);
    oa3 = fmaf(p3, vb[(size_t)(k + 6) * 256], oa3);
  }
  for (; k < NQQ; k += 2)
    oa0 = fmaf(plds[wv][k], vb[(size_t)k * 256], oa0);
  float oa = (oa0 + oa1) + (oa2 + oa3);
  oa += __shfl_xor(oa, 32, 64);
  if (lane < 32)
    out[(size_t)(b * NQQ + q) * 256 + h * 32 + lane] = oa / ssum;
}

// ---------------------------------------------------------------------------
// Cross-attention, all-heads-batched. One block (8 waves, 512 thr) per (b,q).
// Kbuf/Vbuf: [b][p][256] (all heads contiguous per key). Lane l owns dims
// 4l..4l+3 (head l>>3). K/V loads are single coalesced float4 instructions;
// per-head dot = 4 FMA + 3 shfl_xor in 8-lane groups; softmax state lane-local.
// Waves split box rows (x,y); keys walked in z-runs, batches of 8, branch-free.
// blockIdx swizzled so an organ's 27 queries co-locate on one XCD's L2.
__global__ __launch_bounds__(512) void ca_attn(
    const float* __restrict__ qbuf, const float* __restrict__ Kbuf,
    const float* __restrict__ Vbuf, const int* __restrict__ lohi,
    float* __restrict__ out)
{
  __shared__ float wmS[8][8];
  __shared__ float wsS[8][8];
  __shared__ float4 ooS[8][64];

  // --- XCD-grouping swizzle: organ-group (b,org) -> fixed blockIdx%8 class ---
  int xid  = blockIdx.x;        // 0..1079
  int cls  = xid & 7;
  int rest = xid >> 3;          // 0..134
  int gsub = rest / 27;         // 0..4
  int iq   = rest % 27;         // query within organ
  int g    = gsub * 8 + cls;    // organ-group 0..39
  int b    = g / 20;
  int q    = (g % 20) * QPO_ + iq;
  int bid  = b * NQQ + q;

  int wv = threadIdx.x >> 6;
  int lane = threadIdx.x & 63;
  const float scale = 0.17677669529663687f;

  const int* lh = lohi + (size_t)bid * 6;
  int lo0 = lh[0], lo1 = lh[1], lo2 = lh[2];
  int nx = lh[3] - lo0, ny = lh[4] - lo1, nz = lh[5] - lo2;
  int nxy = nx * ny;
  float inv_ny = 1.0f / (float)ny;

  // q fragment: lane l -> dims 4l..4l+3 ; pre-scale by HD^-0.5
  float4 q4 = ((const float4*)(qbuf + (size_t)bid * 256))[lane];
  q4.x *= scale; q4.y *= scale; q4.z *= scale; q4.w *= scale;

  const float* Kb = Kbuf + (size_t)b * PP * 256;
  const float* Vb = Vbuf + (size_t)b * PP * 256;

  float m = -INFINITY, s = 0.f;
  float4 o4 = make_float4(0.f, 0.f, 0.f, 0.f);

  for (int r = wv; r < nxy; r += 8) {
    // r -> (x,y) via float-recip div + fixup
    int x = (int)((float)r * inv_ny);
    int y = r - x * ny;
    if (y < 0)        { x--; y += ny; }
    else if (y >= ny) { x++; y -= ny; }
    int base = (lo0 + x) * (PS1 * PS2) + (lo1 + y) * PS2 + lo2;

    for (int z0 = 0; z0 < nz; z0 += 8) {
      int zrem = nz - z0;
      int zcm1 = (zrem > 8 ? 8 : zrem) - 1;   // last valid i (0..7)

      int pi[8];
      float4 kk[8];
#pragma unroll
      for (int i = 0; i < 8; ++i) {
        pi[i] = base + z0 + (i <= zcm1 ? i : zcm1);
        kk[i] = ((const float4*)(Kb + (size_t)pi[i] * 256))[lane];
      }
      float lg[8];
#pragma unroll
      for (int i = 0; i < 8; ++i) {
        float d = q4.x * kk[i].x;
        d = fmaf(q4.y, kk[i].y, d);
        d = fmaf(q4.z, kk[i].z, d);
        d = fmaf(q4.w, kk[i].w, d);
        d += __shfl_xor(d, 1, 64);
        d += __shfl_xor(d, 2, 64);
        d += __shfl_xor(d, 4, 64);
        lg[i] = (i <= zcm1) ? d : -INFINITY;
      }
      float4 vv[8];
#pragma unroll
      for (int i = 0; i < 8; ++i)
        vv[i] = ((const float4*)(Vb + (size_t)pi[i] * 256))[lane];

      float bm = lg[0];
#pragma unroll
      for (int i = 1; i < 8; ++i) bm = fmaxf(bm, lg[i]);
      float mn = fmaxf(m, bm);
      float f = __expf(m - mn);      // first batch: m=-inf -> f=0
      s *= f; o4.x *= f; o4.y *= f; o4.z *= f; o4.w *= f;
      m = mn;
#pragma unroll
      for (int i = 0; i < 8; ++i) {
        float p = __expf(lg[i] - mn);   // tail lg=-inf -> 0
        s += p;
        o4.x = fmaf(p, vv[i].x, o4.x);
        o4.y = fmaf(p, vv[i].y, o4.y);
        o4.z = fmaf(p, vv[i].z, o4.z);
        o4.w = fmaf(p, vv[i].w, o4.w);
      }
    }
  }

  // ---- merge 8 wave-states (per head) ----
  int hg = lane >> 3, sub = lane & 7;
  if (sub == 0) wmS[wv][hg] = m;
  __syncthreads();
  float M = wmS[0][hg];
#pragma unroll
  for (int w = 1; w < 8; ++w) M = fmaxf(M, wmS[w][hg]);
  float f = __expf(m - M);            // idle wave m=-inf -> f=0
  if (sub == 0) wsS[wv][hg] = s * f;
  ooS[wv][lane] = make_float4(o4.x * f, o4.y * f, o4.z * f, o4.w * f);
  __syncthreads();
  if (threadIdx.x < 64) {
    int l = threadIdx.x;
    int hg2 = l >> 3;
    float4 acc = make_float4(0.f, 0.f, 0.f, 0.f);
    float den = 0.f;
#pragma unroll
    for (int w = 0; w < 8; ++w) {
      float4 t = ooS[w][l];
      acc.x += t.x; acc.y += t.y; acc.z += t.z; acc.w += t.w;
      den += wsS[w][hg2];
    }
    float inv = 1.f / den;
    float4 res = make_float4(acc.x * inv, acc.y * inv, acc.z * inv, acc.w * inv);
    *(float4*)&out[(size_t)bid * 256 + l * 4] = res;
  }
}

// ---------------------------------------------------------------------------
// LayerNorm over D=256: one wave per row. x already contains residual sum.
__global__ __launch_bounds__(256) void ln_kernel(
    const float* __restrict__ x, const float* __restrict__ g,
    const float* __restrict__ bta, float* __restrict__ out)
{
  int wv = threadIdx.x >> 6;
  int lane = threadIdx.x & 63;
  int row = blockIdx.x * 4 + wv;
  const float* xr = x + (size_t)row * 256;
  float v[4];
#pragma unroll
  for (int j = 0; j < 4; ++j) v[j] = xr[lane + 64 * j];
  float s = v[0] + v[1] + v[2] + v[3];
  s = wred_sum(s);
  float mean = s * (1.f / 256.f);
  float vs = 0.f;
#pragma unroll
  for (int j = 0; j < 4; ++j) { float d = v[j] - mean; vs = fmaf(d, d, vs); }
  vs = wred_sum(vs);
  float inv = rsqrtf(vs * (1.f / 256.f) + 1e-5f);
  float* orow = out + (size_t)row * 256;
#pragma unroll
  for (int j = 0; j < 4; ++j) {
    int c = lane + 64 * j;
    orow[c] = (v[j] - mean) * inv * g[c] + bta[c];
  }
}

// ---------------------------------------------------------------------------
// Layer-0 mask boxes from attn_area.
__global__ __launch_bounds__(256) void mask0_kernel(
    const float* __restrict__ area, int* __restrict__ lohi,
    float px, float py, float pz)
{
  int row = blockIdx.x * 256 + threadIdx.x;
  if (row >= MR) return;
  int q = row % NQQ;
  int org = q / QPO_;
  const float* a = area + org * 6;
  int* o = lohi + (size_t)row * 6;
  o[0] = (int)fminf(fmaxf(floorf(a[0] * 20.f - px), 0.f), 20.f);
  o[1] = (int)fminf(fmaxf(floorf(a[1] * 20.f - py), 0.f), 20.f);
  o[2] = (int)fminf(fmaxf(floorf(a[2] * 32.f - pz), 0.f), 32.f);
  o[3] = (int)fminf(fmaxf(floorf(a[3] * 20.f + px), 0.f), 20.f);
  o[4] = (int)fminf(fmaxf(floorf(a[4] * 20.f + py), 0.f), 20.f);
  o[5] = (int)fminf(fmaxf(floorf(a[5] * 32.f + pz), 0.f), 32.f);
}

// ---------------------------------------------------------------------------
// Layers >=1: prop = h2 @ w3.T + b3 -> tanh*0.1 + anchors -> clip -> box ints.
// One wave per (b,q) row.
__global__ __launch_bounds__(256) void mask_reg_kernel(
    const float* __restrict__ h2, const float* __restrict__ w3,
    const float* __restrict__ b3, const float* __restrict__ anchors,
    int* __restrict__ lohi, float px, float py, float pz)
{
  int wv = threadIdx.x >> 6;
  int lane = threadIdx.x & 63;
  int row = blockIdx.x * 4 + wv;
  int q = row % NQQ;
  const float* hr = h2 + (size_t)row * 256;
  float part[6] = {};
#pragma unroll
  for (int j = 0; j < 4; ++j) {
    float hv = hr[lane + 64 * j];
#pragma unroll
    for (int o = 0; o < 6; ++o)
      part[o] = fmaf(hv, w3[o * 256 + lane + 64 * j], part[o]);
  }
#pragma unroll
  for (int o = 0; o < 6; ++o) part[o] = wred_sum(part[o]);
  if (lane == 0) {
    float prop[6];
#pragma unroll
    for (int o = 0; o < 6; ++o) {
      float v = tanhf(part[o] + b3[o]) * 0.1f + anchors[q * 6 + o];
      prop[o] = fminf(fmaxf(v, 0.f), 1.f);
    }
    float vl0 = prop[0] - 0.5f * prop[3], vh0 = prop[0] + 0.5f * prop[3];
    float vl1 = prop[1] - 0.5f * prop[4], vh1 = prop[1] + 0.5f * prop[4];
    float vl2 = prop[2] - 0.5f * prop[5], vh2 = prop[2] + 0.5f * prop[5];
    int* o = lohi + (size_t)row * 6;
    o[0] = (int)fminf(fmaxf(floorf(vl0 * 20.f - px), 0.f), 20.f);
    o[1] = (int)fminf(fmaxf(floorf(vl1 * 20.f - py), 0.f), 20.f);
    o[2] = (int)fminf(fmaxf(floorf(vl2 * 32.f - pz), 0.f), 32.f);
    o[3] = (int)fminf(fmaxf(floorf(vh0 * 20.f + px), 0.f), 20.f);
    o[4] = (int)fminf(fmaxf(floorf(vh1 * 20.f + py), 0.f), 20.f);
    o[5] = (int)fminf(fmaxf(floorf(vh2 * 32.f + pz), 0.f), 32.f);
  }
}

// ---------------------------------------------------------------------------
extern "C" void kernel_launch(void* const* d_in, const int* in_sizes, int n_in,
                              void* d_out, int out_size, void* d_ws, size_t ws_size,
                              hipStream_t stream)
{
  const float* src       = (const float*)d_in[0];
  const float* pos       = (const float*)d_in[1];
  const float* qe        = (const float*)d_in[2];
  const float* sa_in_w   = (const float*)d_in[3];
  const float* sa_in_b   = (const float*)d_in[4];
  const float* sa_out_w  = (const float*)d_in[5];
  const float* sa_out_b  = (const float*)d_in[6];
  const float* ca_k_w    = (const float*)d_in[7];
  const float* ca_v_w    = (const float*)d_in[8];
  const float* ca_proj_w = (const float*)d_in[9];
  const float* ca_proj_b = (const float*)d_in[10];
  const float* ln1_g = (const float*)d_in[11];
  const float* ln1_b = (const float*)d_in[12];
  const float* ln2_g = (const float*)d_in[13];
  const float* ln2_b = (const float*)d_in[14];
  const float* ln3_g = (const float*)d_in[15];
  const float* ln3_b = (const float*)d_in[16];
  const float* ffn_w1 = (const float*)d_in[17];
  const float* ffn_b1 = (const float*)d_in[18];
  const float* ffn_w2 = (const float*)d_in[19];
  const float* ffn_b2 = (const float*)d_in[20];
  const float* reg_w1 = (const float*)d_in[21];
  const float* reg_b1 = (const float*)d_in[22];
  const float* reg_w2 = (const float*)d_in[23];
  const float* reg_b2 = (const float*)d_in[24];
  const float* reg_w3 = (const float*)d_in[25];
  const float* reg_b3 = (const float*)d_in[26];
  const float* anchors   = (const float*)d_in[27];
  const float* attn_area = (const float*)d_in[28];
  float* outp = (float*)d_out;

  float* ws = (float*)d_ws;
  size_t off = 0;
  auto alloc = [&](size_t n) { float* p = ws + off; off += n; return p; };
  float* Kb   = alloc((size_t)BB * PP * 256);  // 26.2 MB, [b][p][256]
  float* Vb   = alloc((size_t)BB * PP * 256);  // 26.2 MB
  float* tgt  = alloc((size_t)MR * DD);
  float* qpos = alloc((size_t)MR * DD);
  float* tmp  = alloc((size_t)MR * DD);
  float* saqk = alloc((size_t)MR * 512);
  float* sav  = alloc((size_t)MR * DD);
  float* sao  = alloc((size_t)MR * DD);
  float* caq  = alloc((size_t)MR * DD);
  float* cao  = alloc((size_t)MR * DD);
  float* mh1  = alloc((size_t)MR * DD);
  float* mh2  = alloc((size_t)MR * DD);
  float* ffh  = alloc((size_t)MR * FFD);
  int*   lohi = (int*)alloc((size_t)MR * 6);
  (void)in_sizes; (void)n_in; (void)out_size; (void)ws_size;

  const float FOCUS_H[6] = {0.1f, 0.075f, 0.05f, 0.05f, 0.025f, 0.025f};

  init_kernel<<<1080, 256, 0, stream>>>(qe, tgt, qpos);

  for (int i = 0; i < LL; ++i) {
    const float* wi  = sa_in_w + (size_t)i * 768 * DD;
    const float* bi  = sa_in_b + (size_t)i * 768;
    // SA: q,k from (tgt+qpos), v from tgt
    gemm_rows<<<dim3(17, 8), 256, 0, stream>>>(tgt, qpos, wi, bi, nullptr, saqk, MR, 512, DD, 0);
    gemm_rows<<<dim3(17, 4), 256, 0, stream>>>(tgt, nullptr, wi + 512 * DD, bi + 512, nullptr, sav, MR, DD, DD, 0);
    sa_attn<<<2160, 256, 0, stream>>>(saqk, sav, sao);
    gemm_rows<<<dim3(17, 4), 256, 0, stream>>>(sao, nullptr, sa_out_w + (size_t)i * DD * DD,
                                               sa_out_b + (size_t)i * DD, tgt, tmp, MR, DD, DD, 0);
    ln_kernel<<<270, 256, 0, stream>>>(tmp, ln2_g + i * DD, ln2_b + i * DD, tgt);

    // mask boxes
    if (i == 0) {
      mask0_kernel<<<5, 256, 0, stream>>>(attn_area, lohi,
          FOCUS_H[0] * PS0, FOCUS_H[0] * PS1, FOCUS_H[0] * PS2);
    } else {
      gemm_rows<<<dim3(17, 4), 256, 0, stream>>>(tgt, nullptr, reg_w1, reg_b1, nullptr, mh1, MR, DD, DD, 1);
      gemm_rows<<<dim3(17, 4), 256, 0, stream>>>(mh1, nullptr, reg_w2, reg_b2, nullptr, mh2, MR, DD, DD, 1);
      mask_reg_kernel<<<270, 256, 0, stream>>>(mh2, reg_w3, reg_b3, anchors, lohi,
          FOCUS_H[i] * PS0, FOCUS_H[i] * PS1, FOCUS_H[i] * PS2);
    }

    // CA: q from (tgt+qpos)@ca_k_w; K from (src+pos)@ca_k_w; V from src@ca_v_w
    gemm_rows<<<dim3(17, 4), 256, 0, stream>>>(tgt, qpos, ca_k_w + (size_t)i * DD * DD,
                                               nullptr, nullptr, caq, MR, DD, DD, 0);
    gemm_kv<<<dim3(200, 4, 2), 256, 0, stream>>>(src, pos, ca_k_w + (size_t)i * DD * DD, Kb);
    gemm_kv<<<dim3(200, 4, 2), 256, 0, stream>>>(src, nullptr, ca_v_w + (size_t)i * DD * DD, Vb);
    ca_attn<<<MR, 512, 0, stream>>>(caq, Kb, Vb, lohi, cao);
    gemm_rows<<<dim3(17, 4), 256, 0, stream>>>(cao, nullptr, ca_proj_w + (size_t)i * DD * DD,
                                               ca_proj_b + (size_t)i * DD, tgt, tmp, MR, DD, DD, 0);
    ln_kernel<<<270, 256, 0, stream>>>(tmp, ln1_g + i * DD, ln1_b + i * DD, tgt);

    // FFN
    gemm_rows<<<dim3(17, 16), 256, 0, stream>>>(tgt, nullptr, ffn_w1 + (size_t)i * FFD * DD,
                                                ffn_b1 + (size_t)i * FFD, nullptr, ffh, MR, FFD, DD, 1);
    gemm_rows<<<dim3(17, 4), 256, 0, stream>>>(ffh, nullptr, ffn_w2 + (size_t)i * DD * FFD,
                                               ffn_b2 + (size_t)i * DD, tgt, tmp, MR, DD, FFD, 0);
    float* lno = (i == LL - 1) ? outp : tgt;
    ln_kernel<<<270, 256, 0, stream>>>(tmp, ln3_g + i * DD, ln3_b + i * DD, lno);
  }
}

// Round 6
// 3709.583 us; speedup vs baseline: 1.4539x; 1.3242x over previous
//
#include <hip/hip_runtime.h>
#include <math.h>

#define BB 2
#define DD 256
#define HH 8
#define HDIM 32
#define FFD 1024
#define LL 6
#define NQQ 540
#define QPO_ 27
#define PS0 20
#define PS1 20
#define PS2 32
#define PP (PS0*PS1*PS2)   // 12800
#define MR (BB*NQQ)        // 1080

static __device__ __forceinline__ float wred_sum(float x) {
#pragma unroll
  for (int off = 32; off; off >>= 1) x += __shfl_xor(x, off, 64);
  return x;
}
static __device__ __forceinline__ float wred_max(float x) {
#pragma unroll
  for (int off = 32; off; off >>= 1) x = fmaxf(x, __shfl_xor(x, off, 64));
  return x;
}

// ---------------------------------------------------------------------------
// init: tgt[b,q,d] = qe[q, 256+d]; qpos[b,q,d] = qe[q, d]
__global__ __launch_bounds__(256) void init_kernel(
    const float* __restrict__ qe, float* __restrict__ tgt, float* __restrict__ qpos)
{
  int idx = blockIdx.x * 256 + threadIdx.x;   // < B*NQ*D == 276480
  int d = idx % DD;
  int q = (idx / DD) % NQQ;
  qpos[idx] = qe[q * 512 + d];
  tgt[idx]  = qe[q * 512 + 256 + d];
}

// ---------------------------------------------------------------------------
// Generic row GEMM: C[r,n] = sum_k (A1[r,k] (+A2[r,k])) * W[n,k] (+bias) (+res) (relu?)
// BM=BN=64, BK=16, 256 threads, 4x4 per thread.
__global__ __launch_bounds__(256) void gemm_rows(
    const float* __restrict__ A1, const float* __restrict__ A2,
    const float* __restrict__ W, const float* __restrict__ bias,
    const float* __restrict__ res, float* __restrict__ C,
    int M, int N, int K, int relu)
{
  __shared__ float a_s[16][65];
  __shared__ float w_s[64][17];
  int bm = blockIdx.x * 64;
  int bn = blockIdx.y * 64;
  int t = threadIdx.x;
  int tp = t & 15, to = t >> 4;
  float acc[4][4] = {};
  for (int k0 = 0; k0 < K; k0 += 16) {
    { // A tile: 64 rows x 16 k, one float4 per thread
      int rl = t >> 2;
      int kq = (t & 3) * 4;
      int r = bm + rl;
      float4 av = make_float4(0.f, 0.f, 0.f, 0.f);
      if (r < M) {
        av = *(const float4*)&A1[(size_t)r * K + k0 + kq];
        if (A2) {
          float4 bv = *(const float4*)&A2[(size_t)r * K + k0 + kq];
          av.x += bv.x; av.y += bv.y; av.z += bv.z; av.w += bv.w;
        }
      }
      a_s[kq + 0][rl] = av.x; a_s[kq + 1][rl] = av.y;
      a_s[kq + 2][rl] = av.z; a_s[kq + 3][rl] = av.w;
    }
    { // W tile: 64 n x 16 k
      int ol = t >> 2;
      int kq = (t & 3) * 4;
      float4 wv = *(const float4*)&W[(size_t)(bn + ol) * K + k0 + kq];
      w_s[ol][kq + 0] = wv.x; w_s[ol][kq + 1] = wv.y;
      w_s[ol][kq + 2] = wv.z; w_s[ol][kq + 3] = wv.w;
    }
    __syncthreads();
#pragma unroll
    for (int d = 0; d < 16; ++d) {
      float a[4], w[4];
#pragma unroll
      for (int i = 0; i < 4; ++i) a[i] = a_s[d][tp * 4 + i];
#pragma unroll
      for (int j = 0; j < 4; ++j) w[j] = w_s[to * 4 + j][d];
#pragma unroll
      for (int i = 0; i < 4; ++i)
#pragma unroll
        for (int j = 0; j < 4; ++j)
          acc[i][j] = fmaf(a[i], w[j], acc[i][j]);
    }
    __syncthreads();
  }
#pragma unroll
  for (int i = 0; i < 4; ++i) {
    int r = bm + tp * 4 + i;
    if (r >= M) continue;
#pragma unroll
    for (int j = 0; j < 4; ++j) {
      int n = bn + to * 4 + j;
      float v = acc[i][j];
      if (bias) v += bias[n];
      if (relu) v = fmaxf(v, 0.f);
      if (res)  v += res[(size_t)r * N + n];
      C[(size_t)r * N + n] = v;
    }
  }
}

// ---------------------------------------------------------------------------
// K/V projection GEMM. A(r=p, k=d) = src[b,d,p] (+pos[b,d,p]); W (256,256) row-major (o,d).
// Output layout: out[b][p][n] (n = h*32+hd contiguous per key) -> float4 stores.
__global__ __launch_bounds__(256) void gemm_kv(
    const float* __restrict__ src, const float* __restrict__ pos,
    const float* __restrict__ W, float* __restrict__ out)
{
  __shared__ float a_s[16][65];
  __shared__ float w_s[64][17];
  int b = blockIdx.z;
  int p0 = blockIdx.x * 64;
  int n0 = blockIdx.y * 64;
  int t = threadIdx.x;
  int tp = t & 15, to = t >> 4;
  const float* sb = src + (size_t)b * DD * PP;
  const float* pb = pos ? pos + (size_t)b * DD * PP : nullptr;
  float acc[4][4] = {};
  for (int k0 = 0; k0 < DD; k0 += 16) {
    { // A tile: a_s[dl][pl] = src[b][k0+dl][p0+pl] (+pos). contiguous in p -> coalesced
      int dl = t >> 4;
      int pq = (t & 15) * 4;
      float4 av = *(const float4*)&sb[(size_t)(k0 + dl) * PP + p0 + pq];
      if (pb) {
        float4 pv = *(const float4*)&pb[(size_t)(k0 + dl) * PP + p0 + pq];
        av.x += pv.x; av.y += pv.y; av.z += pv.z; av.w += pv.w;
      }
      a_s[dl][pq + 0] = av.x; a_s[dl][pq + 1] = av.y;
      a_s[dl][pq + 2] = av.z; a_s[dl][pq + 3] = av.w;
    }
    {
      int ol = t >> 2;
      int kq = (t & 3) * 4;
      float4 wv = *(const float4*)&W[(size_t)(n0 + ol) * DD + k0 + kq];
      w_s[ol][kq + 0] = wv.x; w_s[ol][kq + 1] = wv.y;
      w_s[ol][kq + 2] = wv.z; w_s[ol][kq + 3] = wv.w;
    }
    __syncthreads();
#pragma unroll
    for (int d = 0; d < 16; ++d) {
      float a[4], w[4];
#pragma unroll
      for (int i = 0; i < 4; ++i) a[i] = a_s[d][tp * 4 + i];
#pragma unroll
      for (int j = 0; j < 4; ++j) w[j] = w_s[to * 4 + j][d];
#pragma unroll
      for (int i = 0; i < 4; ++i)
#pragma unroll
        for (int j = 0; j < 4; ++j)
          acc[i][j] = fmaf(a[i], w[j], acc[i][j]);
    }
    __syncthreads();
  }
#pragma unroll
  for (int i = 0; i < 4; ++i) {
    int p = p0 + tp * 4 + i;
    float4 v = make_float4(acc[i][0], acc[i][1], acc[i][2], acc[i][3]);
    *(float4*)&out[((size_t)b * PP + p) * 256 + n0 + to * 4] = v;
  }
}

// ---------------------------------------------------------------------------
// Self-attention, all-heads-batched (same structure as ca_attn, nk=540 fixed,
// no mask). One block (8 waves, 512 thr) per (b,q). Lane l owns dims 4l..4l+3
// (head l>>3). K rows = qkbuf[row*512+256+..] -> coalesced float4; V rows =
// vbuf[row*256+..]. Per-head dot: 4 FMA + 3 shfl_xor in 8-lane groups.
// qkbuf: (MR,512) q cols 0..255, k cols 256..511. vbuf: (MR,256). out: (MR,256).
__global__ __launch_bounds__(512) void sa_attn(
    const float* __restrict__ qkbuf, const float* __restrict__ vbuf,
    float* __restrict__ out)
{
  __shared__ float wmS[8][8];
  __shared__ float wsS[8][8];
  __shared__ float4 ooS[8][64];

  int bid = blockIdx.x;           // b*NQQ + q
  int b = bid / NQQ;
  int wv = threadIdx.x >> 6;
  int lane = threadIdx.x & 63;
  const float scale = 0.17677669529663687f;  // 32^-0.5

  // q fragment: lane l -> dims 4l..4l+3, pre-scaled
  float4 q4 = ((const float4*)(qkbuf + (size_t)bid * 512))[lane];
  q4.x *= scale; q4.y *= scale; q4.z *= scale; q4.w *= scale;

  const float* Kb = qkbuf + (size_t)b * NQQ * 512 + 256;  // k part of rows
  const float* Vb = vbuf + (size_t)b * NQQ * 256;

  float m = -INFINITY, s = 0.f;
  float4 o4 = make_float4(0.f, 0.f, 0.f, 0.f);

  for (int k0 = wv * 8; k0 < NQQ; k0 += 64) {
    int rem = NQQ - k0;
    int zcm1 = (rem > 8 ? 8 : rem) - 1;     // last valid i

    int ki[8];
    float4 kk[8];
#pragma unroll
    for (int i = 0; i < 8; ++i) {
      ki[i] = k0 + (i <= zcm1 ? i : zcm1);
      kk[i] = ((const float4*)(Kb + (size_t)ki[i] * 512))[lane];
    }
    float lg[8];
#pragma unroll
    for (int i = 0; i < 8; ++i) {
      float d = q4.x * kk[i].x;
      d = fmaf(q4.y, kk[i].y, d);
      d = fmaf(q4.z, kk[i].z, d);
      d = fmaf(q4.w, kk[i].w, d);
      d += __shfl_xor(d, 1, 64);
      d += __shfl_xor(d, 2, 64);
      d += __shfl_xor(d, 4, 64);
      lg[i] = (i <= zcm1) ? d : -INFINITY;
    }
    float4 vv[8];
#pragma unroll
    for (int i = 0; i < 8; ++i)
      vv[i] = ((const float4*)(Vb + (size_t)ki[i] * 256))[lane];

    float bm = lg[0];
#pragma unroll
    for (int i = 1; i < 8; ++i) bm = fmaxf(bm, lg[i]);
    float mn = fmaxf(m, bm);
    float f = __expf(m - mn);        // first batch: m=-inf -> f=0
    s *= f; o4.x *= f; o4.y *= f; o4.z *= f; o4.w *= f;
    m = mn;
#pragma unroll
    for (int i = 0; i < 8; ++i) {
      float p = __expf(lg[i] - mn);  // tail lg=-inf -> 0
      s += p;
      o4.x = fmaf(p, vv[i].x, o4.x);
      o4.y = fmaf(p, vv[i].y, o4.y);
      o4.z = fmaf(p, vv[i].z, o4.z);
      o4.w = fmaf(p, vv[i].w, o4.w);
    }
  }

  // ---- merge 8 wave-states (per head) ----
  int hg = lane >> 3, sub = lane & 7;
  if (sub == 0) wmS[wv][hg] = m;
  __syncthreads();
  float M = wmS[0][hg];
#pragma unroll
  for (int w = 1; w < 8; ++w) M = fmaxf(M, wmS[w][hg]);
  float f = __expf(m - M);
  if (sub == 0) wsS[wv][hg] = s * f;
  ooS[wv][lane] = make_float4(o4.x * f, o4.y * f, o4.z * f, o4.w * f);
  __syncthreads();
  if (threadIdx.x < 64) {
    int l = threadIdx.x;
    int hg2 = l >> 3;
    float4 acc = make_float4(0.f, 0.f, 0.f, 0.f);
    float den = 0.f;
#pragma unroll
    for (int w = 0; w < 8; ++w) {
      float4 t = ooS[w][l];
      acc.x += t.x; acc.y += t.y; acc.z += t.z; acc.w += t.w;
      den += wsS[w][hg2];
    }
    float inv = 1.f / den;
    float4 res = make_float4(acc.x * inv, acc.y * inv, acc.z * inv, acc.w * inv);
    *(float4*)&out[(size_t)bid * 256 + l * 4] = res;
  }
}

// ---------------------------------------------------------------------------
// Cross-attention, all-heads-batched. One block (8 waves, 512 thr) per (b,q).
// Kbuf/Vbuf: [b][p][256] (all heads contiguous per key). Lane l owns dims
// 4l..4l+3 (head l>>3). K/V loads are single coalesced float4 instructions;
// per-head dot = 4 FMA + 3 shfl_xor in 8-lane groups; softmax state lane-local.
// Waves split box rows (x,y); keys walked in z-runs, batches of 8, branch-free.
// blockIdx swizzled so an organ's 27 queries co-locate on one XCD's L2.
__global__ __launch_bounds__(512) void ca_attn(
    const float* __restrict__ qbuf, const float* __restrict__ Kbuf,
    const float* __restrict__ Vbuf, const int* __restrict__ lohi,
    float* __restrict__ out)
{
  __shared__ float wmS[8][8];
  __shared__ float wsS[8][8];
  __shared__ float4 ooS[8][64];

  // --- XCD-grouping swizzle: organ-group (b,org) -> fixed blockIdx%8 class ---
  int xid  = blockIdx.x;        // 0..1079
  int cls  = xid & 7;
  int rest = xid >> 3;          // 0..134
  int gsub = rest / 27;         // 0..4
  int iq   = rest % 27;         // query within organ
  int g    = gsub * 8 + cls;    // organ-group 0..39
  int b    = g / 20;
  int q    = (g % 20) * QPO_ + iq;
  int bid  = b * NQQ + q;

  int wv = threadIdx.x >> 6;
  int lane = threadIdx.x & 63;
  const float scale = 0.17677669529663687f;

  const int* lh = lohi + (size_t)bid * 6;
  int lo0 = lh[0], lo1 = lh[1], lo2 = lh[2];
  int nx = lh[3] - lo0, ny = lh[4] - lo1, nz = lh[5] - lo2;
  int nxy = nx * ny;
  float inv_ny = 1.0f / (float)ny;

  // q fragment: lane l -> dims 4l..4l+3 ; pre-scale by HD^-0.5
  float4 q4 = ((const float4*)(qbuf + (size_t)bid * 256))[lane];
  q4.x *= scale; q4.y *= scale; q4.z *= scale; q4.w *= scale;

  const float* Kb = Kbuf + (size_t)b * PP * 256;
  const float* Vb = Vbuf + (size_t)b * PP * 256;

  float m = -INFINITY, s = 0.f;
  float4 o4 = make_float4(0.f, 0.f, 0.f, 0.f);

  for (int r = wv; r < nxy; r += 8) {
    // r -> (x,y) via float-recip div + fixup
    int x = (int)((float)r * inv_ny);
    int y = r - x * ny;
    if (y < 0)        { x--; y += ny; }
    else if (y >= ny) { x++; y -= ny; }
    int base = (lo0 + x) * (PS1 * PS2) + (lo1 + y) * PS2 + lo2;

    for (int z0 = 0; z0 < nz; z0 += 8) {
      int zrem = nz - z0;
      int zcm1 = (zrem > 8 ? 8 : zrem) - 1;   // last valid i (0..7)

      int pi[8];
      float4 kk[8];
#pragma unroll
      for (int i = 0; i < 8; ++i) {
        pi[i] = base + z0 + (i <= zcm1 ? i : zcm1);
        kk[i] = ((const float4*)(Kb + (size_t)pi[i] * 256))[lane];
      }
      float lg[8];
#pragma unroll
      for (int i = 0; i < 8; ++i) {
        float d = q4.x * kk[i].x;
        d = fmaf(q4.y, kk[i].y, d);
        d = fmaf(q4.z, kk[i].z, d);
        d = fmaf(q4.w, kk[i].w, d);
        d += __shfl_xor(d, 1, 64);
        d += __shfl_xor(d, 2, 64);
        d += __shfl_xor(d, 4, 64);
        lg[i] = (i <= zcm1) ? d : -INFINITY;
      }
      float4 vv[8];
#pragma unroll
      for (int i = 0; i < 8; ++i)
        vv[i] = ((const float4*)(Vb + (size_t)pi[i] * 256))[lane];

      float bm = lg[0];
#pragma unroll
      for (int i = 1; i < 8; ++i) bm = fmaxf(bm, lg[i]);
      float mn = fmaxf(m, bm);
      float f = __expf(m - mn);      // first batch: m=-inf -> f=0
      s *= f; o4.x *= f; o4.y *= f; o4.z *= f; o4.w *= f;
      m = mn;
#pragma unroll
      for (int i = 0; i < 8; ++i) {
        float p = __expf(lg[i] - mn);   // tail lg=-inf -> 0
        s += p;
        o4.x = fmaf(p, vv[i].x, o4.x);
        o4.y = fmaf(p, vv[i].y, o4.y);
        o4.z = fmaf(p, vv[i].z, o4.z);
        o4.w = fmaf(p, vv[i].w, o4.w);
      }
    }
  }

  // ---- merge 8 wave-states (per head) ----
  int hg = lane >> 3, sub = lane & 7;
  if (sub == 0) wmS[wv][hg] = m;
  __syncthreads();
  float M = wmS[0][hg];
#pragma unroll
  for (int w = 1; w < 8; ++w) M = fmaxf(M, wmS[w][hg]);
  float f = __expf(m - M);            // idle wave m=-inf -> f=0
  if (sub == 0) wsS[wv][hg] = s * f;
  ooS[wv][lane] = make_float4(o4.x * f, o4.y * f, o4.z * f, o4.w * f);
  __syncthreads();
  if (threadIdx.x < 64) {
    int l = threadIdx.x;
    int hg2 = l >> 3;
    float4 acc = make_float4(0.f, 0.f, 0.f, 0.f);
    float den = 0.f;
#pragma unroll
    for (int w = 0; w < 8; ++w) {
      float4 t = ooS[w][l];
      acc.x += t.x; acc.y += t.y; acc.z += t.z; acc.w += t.w;
      den += wsS[w][hg2];
    }
    float inv = 1.f / den;
    float4 res = make_float4(acc.x * inv, acc.y * inv, acc.z * inv, acc.w * inv);
    *(float4*)&out[(size_t)bid * 256 + l * 4] = res;
  }
}

// ---------------------------------------------------------------------------
// LayerNorm over D=256: one wave per row. x already contains residual sum.
__global__ __launch_bounds__(256) void ln_kernel(
    const float* __restrict__ x, const float* __restrict__ g,
    const float* __restrict__ bta, float* __restrict__ out)
{
  int wv = threadIdx.x >> 6;
  int lane = threadIdx.x & 63;
  int row = blockIdx.x * 4 + wv;
  const float* xr = x + (size_t)row * 256;
  float v[4];
#pragma unroll
  for (int j = 0; j < 4; ++j) v[j] = xr[lane + 64 * j];
  float s = v[0] + v[1] + v[2] + v[3];
  s = wred_sum(s);
  float mean = s * (1.f / 256.f);
  float vs = 0.f;
#pragma unroll
  for (int j = 0; j < 4; ++j) { float d = v[j] - mean; vs = fmaf(d, d, vs); }
  vs = wred_sum(vs);
  float inv = rsqrtf(vs * (1.f / 256.f) + 1e-5f);
  float* orow = out + (size_t)row * 256;
#pragma unroll
  for (int j = 0; j < 4; ++j) {
    int c = lane + 64 * j;
    orow[c] = (v[j] - mean) * inv * g[c] + bta[c];
  }
}

// ---------------------------------------------------------------------------
// Layer-0 mask boxes from attn_area.
__global__ __launch_bounds__(256) void mask0_kernel(
    const float* __restrict__ area, int* __restrict__ lohi,
    float px, float py, float pz)
{
  int row = blockIdx.x * 256 + threadIdx.x;
  if (row >= MR) return;
  int q = row % NQQ;
  int org = q / QPO_;
  const float* a = area + org * 6;
  int* o = lohi + (size_t)row * 6;
  o[0] = (int)fminf(fmaxf(floorf(a[0] * 20.f - px), 0.f), 20.f);
  o[1] = (int)fminf(fmaxf(floorf(a[1] * 20.f - py), 0.f), 20.f);
  o[2] = (int)fminf(fmaxf(floorf(a[2] * 32.f - pz), 0.f), 32.f);
  o[3] = (int)fminf(fmaxf(floorf(a[3] * 20.f + px), 0.f), 20.f);
  o[4] = (int)fminf(fmaxf(floorf(a[4] * 20.f + py), 0.f), 20.f);
  o[5] = (int)fminf(fmaxf(floorf(a[5] * 32.f + pz), 0.f), 32.f);
}

// ---------------------------------------------------------------------------
// Layers >=1: prop = h2 @ w3.T + b3 -> tanh*0.1 + anchors -> clip -> box ints.
// One wave per (b,q) row.
__global__ __launch_bounds__(256) void mask_reg_kernel(
    const float* __restrict__ h2, const float* __restrict__ w3,
    const float* __restrict__ b3, const float* __restrict__ anchors,
    int* __restrict__ lohi, float px, float py, float pz)
{
  int wv = threadIdx.x >> 6;
  int lane = threadIdx.x & 63;
  int row = blockIdx.x * 4 + wv;
  int q = row % NQQ;
  const float* hr = h2 + (size_t)row * 256;
  float part[6] = {};
#pragma unroll
  for (int j = 0; j < 4; ++j) {
    float hv = hr[lane + 64 * j];
#pragma unroll
    for (int o = 0; o < 6; ++o)
      part[o] = fmaf(hv, w3[o * 256 + lane + 64 * j], part[o]);
  }
#pragma unroll
  for (int o = 0; o < 6; ++o) part[o] = wred_sum(part[o]);
  if (lane == 0) {
    float prop[6];
#pragma unroll
    for (int o = 0; o < 6; ++o) {
      float v = tanhf(part[o] + b3[o]) * 0.1f + anchors[q * 6 + o];
      prop[o] = fminf(fmaxf(v, 0.f), 1.f);
    }
    float vl0 = prop[0] - 0.5f * prop[3], vh0 = prop[0] + 0.5f * prop[3];
    float vl1 = prop[1] - 0.5f * prop[4], vh1 = prop[1] + 0.5f * prop[4];
    float vl2 = prop[2] - 0.5f * prop[5], vh2 = prop[2] + 0.5f * prop[5];
    int* o = lohi + (size_t)row * 6;
    o[0] = (int)fminf(fmaxf(floorf(vl0 * 20.f - px), 0.f), 20.f);
    o[1] = (int)fminf(fmaxf(floorf(vl1 * 20.f - py), 0.f), 20.f);
    o[2] = (int)fminf(fmaxf(floorf(vl2 * 32.f - pz), 0.f), 32.f);
    o[3] = (int)fminf(fmaxf(floorf(vh0 * 20.f + px), 0.f), 20.f);
    o[4] = (int)fminf(fmaxf(floorf(vh1 * 20.f + py), 0.f), 20.f);
    o[5] = (int)fminf(fmaxf(floorf(vh2 * 32.f + pz), 0.f), 32.f);
  }
}

// ---------------------------------------------------------------------------
extern "C" void kernel_launch(void* const* d_in, const int* in_sizes, int n_in,
                              void* d_out, int out_size, void* d_ws, size_t ws_size,
                              hipStream_t stream)
{
  const float* src       = (const float*)d_in[0];
  const float* pos       = (const float*)d_in[1];
  const float* qe        = (const float*)d_in[2];
  const float* sa_in_w   = (const float*)d_in[3];
  const float* sa_in_b   = (const float*)d_in[4];
  const float* sa_out_w  = (const float*)d_in[5];
  const float* sa_out_b  = (const float*)d_in[6];
  const float* ca_k_w    = (const float*)d_in[7];
  const float* ca_v_w    = (const float*)d_in[8];
  const float* ca_proj_w = (const float*)d_in[9];
  const float* ca_proj_b = (const float*)d_in[10];
  const float* ln1_g = (const float*)d_in[11];
  const float* ln1_b = (const float*)d_in[12];
  const float* ln2_g = (const float*)d_in[13];
  const float* ln2_b = (const float*)d_in[14];
  const float* ln3_g = (const float*)d_in[15];
  const float* ln3_b = (const float*)d_in[16];
  const float* ffn_w1 = (const float*)d_in[17];
  const float* ffn_b1 = (const float*)d_in[18];
  const float* ffn_w2 = (const float*)d_in[19];
  const float* ffn_b2 = (const float*)d_in[20];
  const float* reg_w1 = (const float*)d_in[21];
  const float* reg_b1 = (const float*)d_in[22];
  const float* reg_w2 = (const float*)d_in[23];
  const float* reg_b2 = (const float*)d_in[24];
  const float* reg_w3 = (const float*)d_in[25];
  const float* reg_b3 = (const float*)d_in[26];
  const float* anchors   = (const float*)d_in[27];
  const float* attn_area = (const float*)d_in[28];
  float* outp = (float*)d_out;

  float* ws = (float*)d_ws;
  size_t off = 0;
  auto alloc = [&](size_t n) { float* p = ws + off; off += n; return p; };
  float* Kb   = alloc((size_t)BB * PP * 256);  // 26.2 MB, [b][p][256]
  float* Vb   = alloc((size_t)BB * PP * 256);  // 26.2 MB
  float* tgt  = alloc((size_t)MR * DD);
  float* qpos = alloc((size_t)MR * DD);
  float* tmp  = alloc((size_t)MR * DD);
  float* saqk = alloc((size_t)MR * 512);
  float* sav  = alloc((size_t)MR * DD);
  float* sao  = alloc((size_t)MR * DD);
  float* caq  = alloc((size_t)MR * DD);
  float* cao  = alloc((size_t)MR * DD);
  float* mh1  = alloc((size_t)MR * DD);
  float* mh2  = alloc((size_t)MR * DD);
  float* ffh  = alloc((size_t)MR * FFD);
  int*   lohi = (int*)alloc((size_t)MR * 6);
  (void)in_sizes; (void)n_in; (void)out_size; (void)ws_size;

  const float FOCUS_H[6] = {0.1f, 0.075f, 0.05f, 0.05f, 0.025f, 0.025f};

  init_kernel<<<1080, 256, 0, stream>>>(qe, tgt, qpos);

  for (int i = 0; i < LL; ++i) {
    const float* wi  = sa_in_w + (size_t)i * 768 * DD;
    const float* bi  = sa_in_b + (size_t)i * 768;
    // SA: q,k from (tgt+qpos), v from tgt
    gemm_rows<<<dim3(17, 8), 256, 0, stream>>>(tgt, qpos, wi, bi, nullptr, saqk, MR, 512, DD, 0);
    gemm_rows<<<dim3(17, 4), 256, 0, stream>>>(tgt, nullptr, wi + 512 * DD, bi + 512, nullptr, sav, MR, DD, DD, 0);
    sa_attn<<<MR, 512, 0, stream>>>(saqk, sav, sao);
    gemm_rows<<<dim3(17, 4), 256, 0, stream>>>(sao, nullptr, sa_out_w + (size_t)i * DD * DD,
                                               sa_out_b + (size_t)i * DD, tgt, tmp, MR, DD, DD, 0);
    ln_kernel<<<270, 256, 0, stream>>>(tmp, ln2_g + i * DD, ln2_b + i * DD, tgt);

    // mask boxes
    if (i == 0) {
      mask0_kernel<<<5, 256, 0, stream>>>(attn_area, lohi,
          FOCUS_H[0] * PS0, FOCUS_H[0] * PS1, FOCUS_H[0] * PS2);
    } else {
      gemm_rows<<<dim3(17, 4), 256, 0, stream>>>(tgt, nullptr, reg_w1, reg_b1, nullptr, mh1, MR, DD, DD, 1);
      gemm_rows<<<dim3(17, 4), 256, 0, stream>>>(mh1, nullptr, reg_w2, reg_b2, nullptr, mh2, MR, DD, DD, 1);
      mask_reg_kernel<<<270, 256, 0, stream>>>(mh2, reg_w3, reg_b3, anchors, lohi,
          FOCUS_H[i] * PS0, FOCUS_H[i] * PS1, FOCUS_H[i] * PS2);
    }

    // CA: q from (tgt+qpos)@ca_k_w; K from (src+pos)@ca_k_w; V from src@ca_v_w
    gemm_rows<<<dim3(17, 4), 256, 0, stream>>>(tgt, qpos, ca_k_w + (size_t)i * DD * DD,
                                               nullptr, nullptr, caq, MR, DD, DD, 0);
    gemm_kv<<<dim3(200, 4, 2), 256, 0, stream>>>(src, pos, ca_k_w + (size_t)i * DD * DD, Kb);
    gemm_kv<<<dim3(200, 4, 2), 256, 0, stream>>>(src, nullptr, ca_v_w + (size_t)i * DD * DD, Vb);
    ca_attn<<<MR, 512, 0, stream>>>(caq, Kb, Vb, lohi, cao);
    gemm_rows<<<dim3(17, 4), 256, 0, stream>>>(cao, nullptr, ca_proj_w + (size_t)i * DD * DD,
                                               ca_proj_b + (size_t)i * DD, tgt, tmp, MR, DD, DD, 0);
    ln_kernel<<<270, 256, 0, stream>>>(tmp, ln1_g + i * DD, ln1_b + i * DD, tgt);

    // FFN
    gemm_rows<<<dim3(17, 16), 256, 0, stream>>>(tgt, nullptr, ffn_w1 + (size_t)i * FFD * DD,
                                                ffn_b1 + (size_t)i * FFD, nullptr, ffh, MR, FFD, DD, 1);
    gemm_rows<<<dim3(17, 4), 256, 0, stream>>>(ffh, nullptr, ffn_w2 + (size_t)i * DD * FFD,
                                               ffn_b2 + (size_t)i * DD, tgt, tmp, MR, DD, FFD, 0);
    float* lno = (i == LL - 1) ? outp : tgt;
    ln_kernel<<<270, 256, 0, stream>>>(tmp, ln3_g + i * DD, ln3_b + i * DD, lno);
  }
}